// Round 4
// baseline (805.794 us; speedup 1.0000x reference)
//
#include <hip/hip_runtime.h>
#include <hip/hip_bf16.h>

typedef short bf16x8 __attribute__((ext_vector_type(8)));
typedef float f32x4  __attribute__((ext_vector_type(4)));

#define T_STEPS 40
#define BATCH   256

__device__ __forceinline__ float bf2f(unsigned short u) {
    union { unsigned int i; float f; } c; c.i = ((unsigned int)u) << 16; return c.f;
}
__device__ __forceinline__ unsigned short f2bf_exact(float f) {
    union { float f; unsigned int i; } c; c.f = f; return (unsigned short)(c.i >> 16);
}
__device__ __forceinline__ unsigned short f2bf_rne(float f) {
    union { float f; unsigned int i; } c; c.f = f;
    unsigned int u = c.i;
    u += 0x7FFFu + ((u >> 16) & 1u);
    return (unsigned short)(u >> 16);
}

// norse LIF step, pinned to mul-then-add fp32 order.
__device__ __forceinline__ float lif_update(float inp, float& v, float& i, float vth) {
    float vd = __fadd_rn(v, __fmul_rn(0.1f, __fsub_rn(i, v)));  // v + dt*tau_m*(i-v)
    float id = __fmul_rn(0.8f, i);                               // i * (1 - dt*tau_s)
    float z  = (vd > vth) ? 1.0f : 0.0f;
    v = (vd > vth) ? 0.0f : vd;
    i = __fadd_rn(id, inp);
    return z;
}

// ---------------------------------------------------------------------------
// Kernel 1: conv1 (fp32, 1->20ch, 3x3, 28->26) + LIF0 + 2x2 avgpool.
// Persistent over t, one sample per block. LIF states in VGPRs.
// Output s0: bf16 (pooled spikes exact in bf16) [pos(169)][ic(24 pad)].
// ---------------------------------------------------------------------------
__global__ __launch_bounds__(576) void k_conv1(
    const float* __restrict__ x,             // [T,B,784] fp32
    const float* __restrict__ w1,            // [20,1,3,3] fp32
    unsigned short* __restrict__ s0)         // [T,B,169,24] bf16
{
    const int b   = blockIdx.x;
    const int tid = threadIdx.x;
    const bool active = tid < 520;
    const int oc = tid % 20;
    const int pr = tid / 20;

    __shared__ __align__(16) float xl[784];
    __shared__ __align__(16) float zl[20*26*26];

    float wr[9];
    if (active) {
        #pragma unroll
        for (int j = 0; j < 9; ++j) wr[j] = w1[oc*9 + j];
    }
    float vs[26], is[26];
    #pragma unroll
    for (int p = 0; p < 26; ++p) { vs[p] = 0.f; is[p] = 0.f; }

    for (int t = 0; t < T_STEPS; ++t) {
        const float* xs = x + (size_t)(t*BATCH + b)*784;
        for (int idx = tid; idx < 784; idx += 576) xl[idx] = xs[idx];
        __syncthreads();
        if (active) {
            float acc[26];
            #pragma unroll
            for (int p = 0; p < 26; ++p) acc[p] = 0.f;
            #pragma unroll
            for (int kr = 0; kr < 3; ++kr) {
                float row[28];
                #pragma unroll
                for (int q = 0; q < 7; ++q)
                    *(float4*)&row[q*4] = *(const float4*)&xl[(pr+kr)*28 + q*4];
                #pragma unroll
                for (int kc = 0; kc < 3; ++kc) {
                    float w = wr[kr*3+kc];
                    #pragma unroll
                    for (int p = 0; p < 26; ++p) acc[p] += row[p+kc] * w;
                }
            }
            #pragma unroll
            for (int p = 0; p < 26; ++p) {
                float z = lif_update(acc[p], vs[p], is[p], 0.2f);
                zl[(oc*26 + pr)*26 + p] = z;
            }
        }
        __syncthreads();
        size_t base = (size_t)(t*BATCH + b) * 4056;  // 169*24
        if (active && pr < 13) {
            #pragma unroll
            for (int q = 0; q < 13; ++q) {
                float s = zl[(oc*26 + 2*pr)*26 + 2*q]     + zl[(oc*26 + 2*pr)*26 + 2*q + 1]
                        + zl[(oc*26 + 2*pr + 1)*26 + 2*q] + zl[(oc*26 + 2*pr + 1)*26 + 2*q + 1];
                s0[base + (size_t)(pr*13 + q)*24 + oc] = f2bf_exact(0.25f * s);
            }
        }
        for (int s2 = tid; s2 < 676; s2 += 576)
            s0[base + (size_t)(s2 >> 2)*24 + 20 + (s2 & 3)] = 0;
        __syncthreads();
    }
}

// ---------------------------------------------------------------------------
// Kernel 2: conv2 (20->50ch, 3x3, 13->11) via bf16 MFMA with 3-plane weight
// split (hi+mid+lo, rep error ~2^-27 — below fp32 noise) + LIF1.
// Persistent over t, one sample per block. M=pos(121->128), N=oc(50->64),
// K=im2col 216 (g-major, ic padded to 24).
// ---------------------------------------------------------------------------
__global__ __launch_bounds__(256, 1) void k_conv2(
    const unsigned short* __restrict__ s0,   // [T,B,169,24] bf16
    const float* __restrict__ w2,            // [50,20,3,3] fp32
    unsigned short* __restrict__ z1)         // [T,B,6080] bf16 spikes
{
    const int b    = blockIdx.x;
    const int tid  = threadIdx.x;
    const int wv   = tid >> 6;
    const int lane = tid & 63;
    const int l15  = lane & 15;
    const int kg   = lane >> 4;

    __shared__ __align__(16) unsigned short w2h[64*232];
    __shared__ __align__(16) unsigned short w2m[64*232];
    __shared__ __align__(16) unsigned short w2l[64*232];
    __shared__ __align__(16) unsigned short sIn[176*24];

    for (int s = tid; s < 64*232; s += 256) {
        int ocw = s / 232, kk = s % 232;
        int g = kk / 24, ic = kk % 24;
        float val = 0.f;
        if (ocw < 50 && g < 9 && ic < 20) val = w2[(ocw*20 + ic)*9 + g];
        unsigned short h = f2bf_rne(val);
        float r1 = val - bf2f(h);
        unsigned short m = f2bf_rne(r1);
        w2h[s] = h;
        w2m[s] = m;
        w2l[s] = f2bf_rne(r1 - bf2f(m));
    }
    for (int s = tid + 4056; s < 4224; s += 256) sIn[s] = 0;
    __syncthreads();

    int addrA[2][7];
    #pragma unroll
    for (int mt = 0; mt < 2; ++mt) {
        int pos = (wv*2 + mt)*16 + l15;
        #pragma unroll
        for (int kt = 0; kt < 7; ++kt) {
            int k = kt*32 + kg*8;
            int g = k / 24, o = k - g*24;
            if (pos <= 120 && g <= 8) {
                int in_idx = pos + 2*(pos/11) + 13*(g/3) + (g % 3);
                addrA[mt][kt] = in_idx*48 + o*2;
            } else addrA[mt][kt] = 172*48;   // zeroed row
        }
    }

    float vst[2][4][4], ist[2][4][4];
    #pragma unroll
    for (int mt = 0; mt < 2; ++mt)
        #pragma unroll
        for (int nt = 0; nt < 4; ++nt)
            #pragma unroll
            for (int r = 0; r < 4; ++r) { vst[mt][nt][r] = 0.f; ist[mt][nt][r] = 0.f; }

    const char* sInB = (const char*)sIn;
    const f32x4 zero4 = {0.f, 0.f, 0.f, 0.f};

    for (int t = 0; t < T_STEPS; ++t) {
        const unsigned int* src = (const unsigned int*)(s0 + (size_t)(t*BATCH + b)*4056);
        unsigned int* dst = (unsigned int*)sIn;
        for (int idx = tid; idx < 2028; idx += 256) dst[idx] = src[idx];
        __syncthreads();

        f32x4 acc[2][4];
        #pragma unroll
        for (int mt = 0; mt < 2; ++mt)
            #pragma unroll
            for (int nt = 0; nt < 4; ++nt) acc[mt][nt] = zero4;

        #pragma unroll
        for (int kt = 0; kt < 7; ++kt) {
            bf16x8 bh[4], bm[4], bl[4];
            #pragma unroll
            for (int nt = 0; nt < 4; ++nt) {
                int n = nt*16 + l15, k = kt*32 + kg*8;
                bh[nt] = *(const bf16x8*)&w2h[n*232 + k];
                bm[nt] = *(const bf16x8*)&w2m[n*232 + k];
                bl[nt] = *(const bf16x8*)&w2l[n*232 + k];
            }
            #pragma unroll
            for (int mt = 0; mt < 2; ++mt) {
                bf16x8 a = *(const bf16x8*)(sInB + addrA[mt][kt]);
                #pragma unroll
                for (int nt = 0; nt < 4; ++nt) {
                    acc[mt][nt] = __builtin_amdgcn_mfma_f32_16x16x32_bf16(
                        a, bh[nt], acc[mt][nt], 0, 0, 0);
                    acc[mt][nt] = __builtin_amdgcn_mfma_f32_16x16x32_bf16(
                        a, bm[nt], acc[mt][nt], 0, 0, 0);
                    acc[mt][nt] = __builtin_amdgcn_mfma_f32_16x16x32_bf16(
                        a, bl[nt], acc[mt][nt], 0, 0, 0);
                }
            }
        }

        size_t rowoff = (size_t)(t*BATCH + b) * 6080;
        #pragma unroll
        for (int mt = 0; mt < 2; ++mt) {
            int posb = (wv*2 + mt)*16 + kg*4;
            #pragma unroll
            for (int nt = 0; nt < 4; ++nt) {
                int ocn = nt*16 + l15;
                #pragma unroll
                for (int r = 0; r < 4; ++r) {
                    float z = lif_update(acc[mt][nt][r], vst[mt][nt][r], ist[mt][nt][r], 0.2f);
                    int pos = posb + r;
                    if (ocn < 50 && pos <= 120)
                        z1[rowoff + ocn*121 + pos] = (z > 0.5f) ? (unsigned short)0x3F80 : (unsigned short)0;
                }
            }
        }
        if (tid < 30) z1[rowoff + 6050 + tid] = 0;
        __syncthreads();
    }
}

// ---------------------------------------------------------------------------
// MFMA GEMM with 3-plane B: C = A * (Bhi + Bmid + Blo)^T  (A bf16-exact,
// fp32 accumulate; rep error ~2^-27). 128x128 tile, BK=64.
// ---------------------------------------------------------------------------
__global__ __launch_bounds__(256, 2) void k_gemm(
    const unsigned short* __restrict__ A,
    const unsigned short* __restrict__ Bhi,
    const unsigned short* __restrict__ Bmid,
    const unsigned short* __restrict__ Blo,
    float* __restrict__ C,
    int Kp, int kiters, int ldc, int nstore)
{
    __shared__ __align__(16) unsigned short As[128*64];
    __shared__ __align__(16) unsigned short Bh[128*64];
    __shared__ __align__(16) unsigned short Bm[128*64];
    __shared__ __align__(16) unsigned short Bl[128*64];
    const int tid  = threadIdx.x;
    const int lane = tid & 63;
    const int wv   = tid >> 6;
    const int wm   = wv & 1, wn = wv >> 1;
    const int l15  = lane & 15, kg = lane >> 4;
    const int mbase = blockIdx.x * 128;
    const int nbase = blockIdx.y * 128;

    const f32x4 zero4 = {0.f, 0.f, 0.f, 0.f};
    f32x4 acc[4][4];
    #pragma unroll
    for (int mt = 0; mt < 4; ++mt)
        #pragma unroll
        for (int nt = 0; nt < 4; ++nt) acc[mt][nt] = zero4;

    const int rowA  = tid >> 3;        // 0..31
    const int chunk = (tid & 7) * 8;   // k-elem offset within 64 slab

    for (int ki = 0; ki < kiters; ++ki) {
        int kb = ki * 64;
        bf16x8 ra[4], rh[4], rm[4], rl[4];
        #pragma unroll
        for (int c = 0; c < 4; ++c) {
            int row = c*32 + rowA;
            ra[c] = *(const bf16x8*)(A    + (size_t)(mbase + row)*Kp + kb + chunk);
            rh[c] = *(const bf16x8*)(Bhi  + (size_t)(nbase + row)*Kp + kb + chunk);
            rm[c] = *(const bf16x8*)(Bmid + (size_t)(nbase + row)*Kp + kb + chunk);
            rl[c] = *(const bf16x8*)(Blo  + (size_t)(nbase + row)*Kp + kb + chunk);
        }
        #pragma unroll
        for (int c = 0; c < 4; ++c) {
            int row = c*32 + rowA;
            *(bf16x8*)&As[row*64 + chunk] = ra[c];
            *(bf16x8*)&Bh[row*64 + chunk] = rh[c];
            *(bf16x8*)&Bm[row*64 + chunk] = rm[c];
            *(bf16x8*)&Bl[row*64 + chunk] = rl[c];
        }
        __syncthreads();
        #pragma unroll
        for (int kt = 0; kt < 2; ++kt) {
            bf16x8 bhv[4], bmv[4], blv[4], afv[4];
            #pragma unroll
            for (int nt = 0; nt < 4; ++nt) {
                bhv[nt] = *(const bf16x8*)&Bh[(wn*64 + nt*16 + l15)*64 + kt*32 + kg*8];
                bmv[nt] = *(const bf16x8*)&Bm[(wn*64 + nt*16 + l15)*64 + kt*32 + kg*8];
                blv[nt] = *(const bf16x8*)&Bl[(wn*64 + nt*16 + l15)*64 + kt*32 + kg*8];
            }
            #pragma unroll
            for (int mt = 0; mt < 4; ++mt)
                afv[mt] = *(const bf16x8*)&As[(wm*64 + mt*16 + l15)*64 + kt*32 + kg*8];
            #pragma unroll
            for (int mt = 0; mt < 4; ++mt)
                #pragma unroll
                for (int nt = 0; nt < 4; ++nt) {
                    acc[mt][nt] = __builtin_amdgcn_mfma_f32_16x16x32_bf16(
                        afv[mt], bhv[nt], acc[mt][nt], 0, 0, 0);
                    acc[mt][nt] = __builtin_amdgcn_mfma_f32_16x16x32_bf16(
                        afv[mt], bmv[nt], acc[mt][nt], 0, 0, 0);
                    acc[mt][nt] = __builtin_amdgcn_mfma_f32_16x16x32_bf16(
                        afv[mt], blv[nt], acc[mt][nt], 0, 0, 0);
                }
        }
        __syncthreads();
    }

    #pragma unroll
    for (int mt = 0; mt < 4; ++mt) {
        int m0 = mbase + wm*64 + mt*16 + kg*4;
        #pragma unroll
        for (int nt = 0; nt < 4; ++nt) {
            int n = nbase + wn*64 + nt*16 + l15;
            if (n < nstore) {
                #pragma unroll
                for (int r = 0; r < 4; ++r)
                    C[(size_t)(m0 + r)*ldc + n] = acc[mt][nt][r];
            }
        }
    }
}

// Pack fp32 weights [N,K] -> zero-padded bf16 hi/mid/lo planes [Npad,Kp]
__global__ void k_pack(const float* __restrict__ src,
                       unsigned short* __restrict__ hi, unsigned short* __restrict__ mid,
                       unsigned short* __restrict__ lo,
                       int N, int K, int Kp, int total) {
    int idx = blockIdx.x*256 + threadIdx.x;
    if (idx >= total) return;
    int n = idx / Kp, k = idx - n*Kp;
    float v = (n < N && k < K) ? src[n*K + k] : 0.f;
    unsigned short h = f2bf_rne(v);
    float r1 = v - bf2f(h);
    unsigned short m = f2bf_rne(r1);
    hi[idx]  = h;
    mid[idx] = m;
    lo[idx]  = f2bf_rne(r1 - bf2f(m));
}

// LIF scan over t for fc layers (states in regs)
__global__ __launch_bounds__(512) void k_lif_scan(
    const float* __restrict__ cin, unsigned short* __restrict__ zout,
    int ld, int nvalid, float vth)
{
    int b = blockIdx.x;
    int n = threadIdx.x;
    float v = 0.f, cur = 0.f;
    for (int t = 0; t < T_STEPS; ++t) {
        size_t idx = (size_t)(t*BATCH + b)*ld + n;
        float z = lif_update(cin[idx], v, cur, vth);
        zout[idx] = (n < nvalid && z > 0.5f) ? (unsigned short)0x3F80 : (unsigned short)0;
    }
}

// LI output cell scan: out[t] = decayed membrane voltage, fp32
__global__ void k_li(const float* __restrict__ c4, float* __restrict__ out) {
    int g = blockIdx.x*64 + threadIdx.x;
    if (g >= 2560) return;
    int b = g / 10, n = g - b*10;
    float vo = 0.f, io = 0.f;
    for (int t = 0; t < T_STEPS; ++t) {
        float vd = __fadd_rn(vo, __fmul_rn(0.1f, __fsub_rn(io, vo)));
        out[(size_t)(t*BATCH + b)*10 + n] = vd;
        io = __fadd_rn(__fmul_rn(0.8f, io), c4[(size_t)(t*BATCH + b)*16 + n]);
        vo = vd;
    }
}

extern "C" void kernel_launch(void* const* d_in, const int* in_sizes, int n_in,
                              void* d_out, int out_size, void* d_ws, size_t ws_size,
                              hipStream_t stream) {
    (void)in_sizes; (void)n_in; (void)out_size; (void)ws_size;
    const float* x   = (const float*)d_in[0];
    const float* w1  = (const float*)d_in[1];
    const float* w2  = (const float*)d_in[2];
    const float* wf1 = (const float*)d_in[3];
    const float* wf2 = (const float*)d_in[4];
    const float* wfo = (const float*)d_in[5];
    char* ws = (char*)d_ws;

    // Region 0 [0, 83,066,880): s0 during conv phase; reused afterwards for
    // fc intermediates + packed weight planes (packed after conv2 consumes s0).
    unsigned short* s0    = (unsigned short*)(ws);             // [10240][4056] bf16
    float*          c2    = (float*)(ws);                      // [10240][512] fp32
    unsigned short* z2    = (unsigned short*)(ws + 20971520);  // [10240][512] bf16
    float*          c3    = (float*)(ws + 31457280);           // [10240][256] fp32
    unsigned short* z3    = (unsigned short*)(ws + 41943040);  // [10240][256] bf16
    float*          c4    = (float*)(ws + 47185920);           // [10240][16]  fp32
    unsigned short* W1hi  = (unsigned short*)(ws + 50331648);  // [512][6080] bf16
    unsigned short* W1mid = (unsigned short*)(ws + 56557568);
    unsigned short* W1lo  = (unsigned short*)(ws + 62783488);
    unsigned short* W2hi  = (unsigned short*)(ws + 69009408);  // [256][512]
    unsigned short* W2mid = (unsigned short*)(ws + 69271552);
    unsigned short* W2lo  = (unsigned short*)(ws + 69533696);
    unsigned short* Wohi  = (unsigned short*)(ws + 69795840);  // [128][256]
    unsigned short* Womid = (unsigned short*)(ws + 69861376);
    unsigned short* Wolo  = (unsigned short*)(ws + 69926912);  // ends 69,992,448
    // Region 1: z1 spikes [10240][6080] bf16, ends at 207,585,280
    unsigned short* z1    = (unsigned short*)(ws + 83066880);

    k_conv1<<<256, 576, 0, stream>>>(x, w1, s0);
    k_conv2<<<256, 256, 0, stream>>>(s0, w2, z1);

    k_pack<<<(3112960+255)/256, 256, 0, stream>>>(wf1, W1hi, W1mid, W1lo, 500, 6050, 6080, 3112960);
    k_pack<<<(131072+255)/256,  256, 0, stream>>>(wf2, W2hi, W2mid, W2lo, 200, 500,  512,  131072);
    k_pack<<<(32768+255)/256,   256, 0, stream>>>(wfo, Wohi, Womid, Wolo, 10,  200,  256,  32768);

    k_gemm<<<dim3(80,4), 256, 0, stream>>>(z1, W1hi, W1mid, W1lo, c2, 6080, 95, 512, 512);
    k_lif_scan<<<256, 512, 0, stream>>>(c2, z2, 512, 500, 0.1f);
    k_gemm<<<dim3(80,2), 256, 0, stream>>>(z2, W2hi, W2mid, W2lo, c3, 512, 8, 256, 256);
    k_lif_scan<<<256, 256, 0, stream>>>(c3, z3, 256, 200, 0.05f);
    k_gemm<<<dim3(80,1), 256, 0, stream>>>(z3, Wohi, Womid, Wolo, c4, 256, 4, 16, 16);
    k_li<<<40, 64, 0, stream>>>(c4, (float*)d_out);
}

// Round 6
// 755.469 us; speedup vs baseline: 1.0666x; 1.0666x over previous
//
#include <hip/hip_runtime.h>
#include <hip/hip_bf16.h>

typedef short bf16x8 __attribute__((ext_vector_type(8)));
typedef float f32x4  __attribute__((ext_vector_type(4)));

#define T_STEPS 40
#define BATCH   256

__device__ __forceinline__ float bf2f(unsigned short u) {
    union { unsigned int i; float f; } c; c.i = ((unsigned int)u) << 16; return c.f;
}
__device__ __forceinline__ unsigned short f2bf_exact(float f) {
    union { float f; unsigned int i; } c; c.f = f; return (unsigned short)(c.i >> 16);
}
__device__ __forceinline__ unsigned short f2bf_rne(float f) {
    union { float f; unsigned int i; } c; c.f = f;
    unsigned int u = c.i;
    u += 0x7FFFu + ((u >> 16) & 1u);
    return (unsigned short)(u >> 16);
}

// norse LIF step, pinned to mul-then-add fp32 order.
__device__ __forceinline__ float lif_update(float inp, float& v, float& i, float vth) {
    float vd = __fadd_rn(v, __fmul_rn(0.1f, __fsub_rn(i, v)));
    float id = __fmul_rn(0.8f, i);
    float z  = (vd > vth) ? 1.0f : 0.0f;
    v = (vd > vth) ? 0.0f : vd;
    i = __fadd_rn(id, inp);
    return z;
}

__device__ __forceinline__ void llds16(const unsigned short* g, void* l) {
    __builtin_amdgcn_global_load_lds(
        (const __attribute__((address_space(1))) unsigned int*)g,
        (__attribute__((address_space(3))) unsigned int*)l, 16, 0, 0);
}

// ---------------------------------------------------------------------------
// Kernel 1: conv1 (fp32) + LIF0 + 2x2 avgpool, persistent over t.
// ---------------------------------------------------------------------------
__global__ __launch_bounds__(576) void k_conv1(
    const float* __restrict__ x,             // [T,B,784] fp32
    const float* __restrict__ w1,            // [20,1,3,3] fp32
    unsigned short* __restrict__ s0)         // [T,B,169,24] bf16
{
    const int b   = blockIdx.x;
    const int tid = threadIdx.x;
    const bool active = tid < 520;
    const int oc = tid % 20;
    const int pr = tid / 20;

    __shared__ __align__(16) float xl[784];
    __shared__ __align__(16) float zl[20*26*26];

    float wr[9];
    if (active) {
        #pragma unroll
        for (int j = 0; j < 9; ++j) wr[j] = w1[oc*9 + j];
    }
    float vs[26], is[26];
    #pragma unroll
    for (int p = 0; p < 26; ++p) { vs[p] = 0.f; is[p] = 0.f; }

    for (int t = 0; t < T_STEPS; ++t) {
        const float* xs = x + (size_t)(t*BATCH + b)*784;
        for (int idx = tid; idx < 784; idx += 576) xl[idx] = xs[idx];
        __syncthreads();
        if (active) {
            float acc[26];
            #pragma unroll
            for (int p = 0; p < 26; ++p) acc[p] = 0.f;
            #pragma unroll
            for (int kr = 0; kr < 3; ++kr) {
                float row[28];
                #pragma unroll
                for (int q = 0; q < 7; ++q)
                    *(float4*)&row[q*4] = *(const float4*)&xl[(pr+kr)*28 + q*4];
                #pragma unroll
                for (int kc = 0; kc < 3; ++kc) {
                    float w = wr[kr*3+kc];
                    #pragma unroll
                    for (int p = 0; p < 26; ++p) acc[p] += row[p+kc] * w;
                }
            }
            #pragma unroll
            for (int p = 0; p < 26; ++p) {
                float z = lif_update(acc[p], vs[p], is[p], 0.2f);
                zl[(oc*26 + pr)*26 + p] = z;
            }
        }
        __syncthreads();
        size_t base = (size_t)(t*BATCH + b) * 4056;  // 169*24
        if (active && pr < 13) {
            #pragma unroll
            for (int q = 0; q < 13; ++q) {
                float s = zl[(oc*26 + 2*pr)*26 + 2*q]     + zl[(oc*26 + 2*pr)*26 + 2*q + 1]
                        + zl[(oc*26 + 2*pr + 1)*26 + 2*q] + zl[(oc*26 + 2*pr + 1)*26 + 2*q + 1];
                s0[base + (size_t)(pr*13 + q)*24 + oc] = f2bf_exact(0.25f * s);
            }
        }
        for (int s2 = tid; s2 < 676; s2 += 576)
            s0[base + (size_t)(s2 >> 2)*24 + 20 + (s2 & 3)] = 0;
        __syncthreads();
    }
}

// ---------------------------------------------------------------------------
// Kernel 2: conv2 via bf16 MFMA, 3-plane weights (hi persistent in VGPR,
// mid/lo from LDS) + LIF1. Wave grid 2m x 2n: mt=4, nt=2 per wave.
// ---------------------------------------------------------------------------
__global__ __launch_bounds__(256, 1) void k_conv2(
    const unsigned short* __restrict__ s0,   // [T,B,169,24] bf16
    const float* __restrict__ w2,            // [50,20,3,3] fp32
    unsigned short* __restrict__ z1)         // [T,B,6080] bf16 spikes
{
    const int b    = blockIdx.x;
    const int tid  = threadIdx.x;
    const int wv   = tid >> 6;
    const int lane = tid & 63;
    const int l15  = lane & 15;
    const int kg   = lane >> 4;
    const int wm   = wv & 1;
    const int wn   = wv >> 1;

    __shared__ __align__(16) unsigned short w2h[64*232];
    __shared__ __align__(16) unsigned short w2m[64*232];
    __shared__ __align__(16) unsigned short w2l[64*232];
    __shared__ __align__(16) unsigned short sIn[200*24];   // rows 169..199 zeroed

    for (int s = tid; s < 64*232; s += 256) {
        int ocw = s / 232, kk = s % 232;
        int g = kk / 24, ic = kk % 24;
        float val = 0.f;
        if (ocw < 50 && g < 9 && ic < 20) val = w2[(ocw*20 + ic)*9 + g];
        unsigned short h = f2bf_rne(val);
        float r1 = val - bf2f(h);
        unsigned short m = f2bf_rne(r1);
        w2h[s] = h;
        w2m[s] = m;
        w2l[s] = f2bf_rne(r1 - bf2f(m));
    }
    for (int s = tid + 4056; s < 4800; s += 256) sIn[s] = 0;
    __syncthreads();

    bf16x8 bfrH[2][7];
    #pragma unroll
    for (int nt = 0; nt < 2; ++nt) {
        int n = (wn*2 + nt)*16 + l15;
        #pragma unroll
        for (int kt = 0; kt < 7; ++kt)
            bfrH[nt][kt] = *(const bf16x8*)&w2h[n*232 + kt*32 + kg*8];
    }

    int addrA[4][7];
    #pragma unroll
    for (int mt = 0; mt < 4; ++mt) {
        int pos = (wm*4 + mt)*16 + l15;
        #pragma unroll
        for (int kt = 0; kt < 7; ++kt) {
            int k = kt*32 + kg*8;
            int g = k / 24, o = k - g*24;
            if (pos <= 120 && g <= 8) {
                int in_idx = pos + 2*(pos/11) + 13*(g/3) + (g % 3);
                addrA[mt][kt] = in_idx*48 + o*2;
            } else addrA[mt][kt] = 180*48;   // zeroed row
        }
    }

    float vst[4][2][4], ist[4][2][4];
    #pragma unroll
    for (int mt = 0; mt < 4; ++mt)
        #pragma unroll
        for (int nt = 0; nt < 2; ++nt)
            #pragma unroll
            for (int r = 0; r < 4; ++r) { vst[mt][nt][r] = 0.f; ist[mt][nt][r] = 0.f; }

    const char* sInB = (const char*)sIn;
    const f32x4 zero4 = {0.f, 0.f, 0.f, 0.f};

    for (int t = 0; t < T_STEPS; ++t) {
        const unsigned int* src = (const unsigned int*)(s0 + (size_t)(t*BATCH + b)*4056);
        unsigned int* dst = (unsigned int*)sIn;
        for (int idx = tid; idx < 2028; idx += 256) dst[idx] = src[idx];
        __syncthreads();

        f32x4 acc[4][2];
        #pragma unroll
        for (int mt = 0; mt < 4; ++mt)
            #pragma unroll
            for (int nt = 0; nt < 2; ++nt) acc[mt][nt] = zero4;

        #pragma unroll
        for (int kt = 0; kt < 7; ++kt) {
            bf16x8 bm[2], bl[2];
            #pragma unroll
            for (int nt = 0; nt < 2; ++nt) {
                int n = (wn*2 + nt)*16 + l15, k = kt*32 + kg*8;
                bm[nt] = *(const bf16x8*)&w2m[n*232 + k];
                bl[nt] = *(const bf16x8*)&w2l[n*232 + k];
            }
            #pragma unroll
            for (int mt = 0; mt < 4; ++mt) {
                bf16x8 a = *(const bf16x8*)(sInB + addrA[mt][kt]);
                #pragma unroll
                for (int nt = 0; nt < 2; ++nt) {
                    acc[mt][nt] = __builtin_amdgcn_mfma_f32_16x16x32_bf16(
                        a, bfrH[nt][kt], acc[mt][nt], 0, 0, 0);
                    acc[mt][nt] = __builtin_amdgcn_mfma_f32_16x16x32_bf16(
                        a, bm[nt], acc[mt][nt], 0, 0, 0);
                    acc[mt][nt] = __builtin_amdgcn_mfma_f32_16x16x32_bf16(
                        a, bl[nt], acc[mt][nt], 0, 0, 0);
                }
            }
        }

        size_t rowoff = (size_t)(t*BATCH + b) * 6080;
        #pragma unroll
        for (int mt = 0; mt < 4; ++mt) {
            int posb = (wm*4 + mt)*16 + kg*4;
            #pragma unroll
            for (int nt = 0; nt < 2; ++nt) {
                int ocn = (wn*2 + nt)*16 + l15;
                #pragma unroll
                for (int r = 0; r < 4; ++r) {
                    float z = lif_update(acc[mt][nt][r], vst[mt][nt][r], ist[mt][nt][r], 0.2f);
                    int pos = posb + r;
                    if (ocn < 50 && pos <= 120)
                        z1[rowoff + ocn*121 + pos] = (z > 0.5f) ? (unsigned short)0x3F80 : (unsigned short)0;
                }
            }
        }
        if (tid < 30) z1[rowoff + 6050 + tid] = 0;
        __syncthreads();
    }
}

// ---------------------------------------------------------------------------
// MFMA GEMM, m97 2-buffer, global_load_lds w16. blockIdx.z selects the
// weight plane (hi/mid/lo) -> partial output C + z*strideC. 128x128, BK=64.
// ---------------------------------------------------------------------------
__global__ __launch_bounds__(256, 3) void k_gemm(
    const unsigned short* __restrict__ A,
    const unsigned short* __restrict__ B0,
    float* __restrict__ C0,
    int Kp, int kiters, int ldc, int nstore,
    size_t strideB, size_t strideC)
{
    __shared__ __align__(16) unsigned short As[128*64];
    __shared__ __align__(16) unsigned short Bs[128*64];
    const unsigned short* B = B0 + (size_t)blockIdx.z * strideB;
    float* C = C0 + (size_t)blockIdx.z * strideC;

    const int tid  = threadIdx.x;
    const int lane = tid & 63;
    const int wv   = tid >> 6;
    const int wm   = wv & 1, wn = wv >> 1;
    const int l15  = lane & 15, kg = lane >> 4;
    const int mbase = blockIdx.x * 128;
    const int nbase = blockIdx.y * 128;

    const f32x4 zero4 = {0.f, 0.f, 0.f, 0.f};
    f32x4 acc[4][4];
    #pragma unroll
    for (int mt = 0; mt < 4; ++mt)
        #pragma unroll
        for (int nt = 0; nt < 4; ++nt) acc[mt][nt] = zero4;

    const int rowA  = tid >> 3;        // 0..31
    const int chunk = (tid & 7) * 8;   // k-elem offset within 64 slab
    char* ldsA = (char*)As + (size_t)wv*1024;
    char* ldsB = (char*)Bs + (size_t)wv*1024;

    for (int ki = 0; ki < kiters; ++ki) {
        int kb = ki * 64;
        #pragma unroll
        for (int c = 0; c < 4; ++c) {
            int row = c*32 + rowA;
            llds16(A + (size_t)(mbase + row)*Kp + kb + chunk, ldsA + c*4096);
            llds16(B + (size_t)(nbase + row)*Kp + kb + chunk, ldsB + c*4096);
        }
        __syncthreads();
        #pragma unroll
        for (int kt = 0; kt < 2; ++kt) {
            bf16x8 bfv[4], afv[4];
            #pragma unroll
            for (int nt = 0; nt < 4; ++nt)
                bfv[nt] = *(const bf16x8*)&Bs[(wn*64 + nt*16 + l15)*64 + kt*32 + kg*8];
            #pragma unroll
            for (int mt = 0; mt < 4; ++mt)
                afv[mt] = *(const bf16x8*)&As[(wm*64 + mt*16 + l15)*64 + kt*32 + kg*8];
            #pragma unroll
            for (int mt = 0; mt < 4; ++mt)
                #pragma unroll
                for (int nt = 0; nt < 4; ++nt)
                    acc[mt][nt] = __builtin_amdgcn_mfma_f32_16x16x32_bf16(
                        afv[mt], bfv[nt], acc[mt][nt], 0, 0, 0);
        }
        __syncthreads();
    }

    #pragma unroll
    for (int mt = 0; mt < 4; ++mt) {
        int m0 = mbase + wm*64 + mt*16 + kg*4;
        #pragma unroll
        for (int nt = 0; nt < 4; ++nt) {
            int n = nbase + wn*64 + nt*16 + l15;
            if (n < nstore) {
                #pragma unroll
                for (int r = 0; r < 4; ++r)
                    C[(size_t)(m0 + r)*ldc + n] = acc[mt][nt][r];
            }
        }
    }
}

// Pack fp32 weights [N,K] -> zero-padded bf16 hi/mid/lo planes [Npad,Kp]
__global__ void k_pack(const float* __restrict__ src,
                       unsigned short* __restrict__ hi, unsigned short* __restrict__ mid,
                       unsigned short* __restrict__ lo,
                       int N, int K, int Kp, int total) {
    int idx = blockIdx.x*256 + threadIdx.x;
    if (idx >= total) return;
    int n = idx / Kp, k = idx - n*Kp;
    float v = (n < N && k < K) ? src[n*K + k] : 0.f;
    unsigned short h = f2bf_rne(v);
    float r1 = v - bf2f(h);
    unsigned short m = f2bf_rne(r1);
    hi[idx]  = h;
    mid[idx] = m;
    lo[idx]  = f2bf_rne(r1 - bf2f(m));
}

// LIF scan over t for fc layers: sums 3 plane-partials, runs LIF recurrence.
__global__ __launch_bounds__(512) void k_lif_scan(
    const float* __restrict__ c0, size_t pstride,
    unsigned short* __restrict__ zout,
    int ld, int nvalid, float vth)
{
    int b = blockIdx.x;
    int n = threadIdx.x;
    float v = 0.f, cur = 0.f;
    for (int t = 0; t < T_STEPS; ++t) {
        size_t idx = (size_t)(t*BATCH + b)*ld + n;
        float s = __fadd_rn(__fadd_rn(c0[idx], c0[idx + pstride]), c0[idx + 2*pstride]);
        float z = lif_update(s, v, cur, vth);
        zout[idx] = (n < nvalid && z > 0.5f) ? (unsigned short)0x3F80 : (unsigned short)0;
    }
}

// LI output cell scan: sums 3 plane-partials; out[t] = decayed membrane (fp32)
__global__ void k_li(const float* __restrict__ c0, size_t pstride, float* __restrict__ out) {
    int g = blockIdx.x*64 + threadIdx.x;
    if (g >= 2560) return;
    int b = g / 10, n = g - b*10;
    float vo = 0.f, io = 0.f;
    for (int t = 0; t < T_STEPS; ++t) {
        size_t idx = (size_t)(t*BATCH + b)*16 + n;
        float s = __fadd_rn(__fadd_rn(c0[idx], c0[idx + pstride]), c0[idx + 2*pstride]);
        float vd = __fadd_rn(vo, __fmul_rn(0.1f, __fsub_rn(io, vo)));
        out[(size_t)(t*BATCH + b)*10 + n] = vd;
        io = __fadd_rn(__fmul_rn(0.8f, io), s);
        vo = vd;
    }
}

extern "C" void kernel_launch(void* const* d_in, const int* in_sizes, int n_in,
                              void* d_out, int out_size, void* d_ws, size_t ws_size,
                              hipStream_t stream) {
    (void)in_sizes; (void)n_in; (void)out_size; (void)ws_size;
    const float* x   = (const float*)d_in[0];
    const float* w1  = (const float*)d_in[1];
    const float* w2  = (const float*)d_in[2];
    const float* wf1 = (const float*)d_in[3];
    const float* wf2 = (const float*)d_in[4];
    const float* wfo = (const float*)d_in[5];
    char* ws = (char*)d_ws;

    // ---- workspace layout (footprint <= 207,585,280 B, proven safe) ----
    // phase A (conv): z1 @0 [0,124.5M), s0 @124,518,400 [.., 207,585,280)
    // phase B (fc1):  z1 live; W planes + c2p overlay dead s0.
    // phase C (fc2+): z1 dead; all buffers disjoint (z3 overlap bug fixed):
    //   z2  [0, 10,485,760)
    //   c3p [10,485,760, 41,943,040)    3 x [10240][256] fp32
    //   z3  [41,943,040, 47,185,920)    [10240][256] bf16
    //   c4p [47,185,920, 49,152,000)    3 x [10240][16] fp32
    unsigned short* z1    = (unsigned short*)(ws);
    unsigned short* s0    = (unsigned short*)(ws + 124518400);
    unsigned short* W1hi  = (unsigned short*)(ws + 124518400);  // 3 x [512][6080]
    unsigned short* W2hi  = (unsigned short*)(ws + 143196160);  // 3 x [256][512]
    unsigned short* Wohi  = (unsigned short*)(ws + 143982592);  // 3 x [128][256]
    float*          c2p   = (float*)(ws + 144179200);           // 3 x [10240][512] fp32
    unsigned short* z2    = (unsigned short*)(ws);
    float*          c3p   = (float*)(ws + 10485760);
    unsigned short* z3    = (unsigned short*)(ws + 41943040);
    float*          c4p   = (float*)(ws + 47185920);

    k_conv1<<<256, 576, 0, stream>>>(x, w1, s0);
    k_conv2<<<256, 256, 0, stream>>>(s0, w2, z1);

    k_pack<<<(3112960+255)/256, 256, 0, stream>>>(wf1, W1hi, W1hi+3112960, W1hi+6225920, 500, 6050, 6080, 3112960);
    k_pack<<<(131072+255)/256,  256, 0, stream>>>(wf2, W2hi, W2hi+131072,  W2hi+262144,  200, 500,  512,  131072);
    k_pack<<<(32768+255)/256,   256, 0, stream>>>(wfo, Wohi, Wohi+32768,   Wohi+65536,   10,  200,  256,  32768);

    k_gemm<<<dim3(80,4,3), 256, 0, stream>>>(z1, W1hi, c2p, 6080, 95, 512, 512,
                                             (size_t)3112960, (size_t)5242880);
    k_lif_scan<<<256, 512, 0, stream>>>(c2p, (size_t)5242880, z2, 512, 500, 0.1f);
    k_gemm<<<dim3(80,2,3), 256, 0, stream>>>(z2, W2hi, c3p, 512, 8, 256, 256,
                                             (size_t)131072, (size_t)2621440);
    k_lif_scan<<<256, 256, 0, stream>>>(c3p, (size_t)2621440, z3, 256, 200, 0.05f);
    k_gemm<<<dim3(80,1,3), 256, 0, stream>>>(z3, Wohi, c4p, 256, 4, 16, 16,
                                             (size_t)32768, (size_t)163840);
    k_li<<<40, 64, 0, stream>>>(c4p, (size_t)163840, (float*)d_out);
}

// Round 7
// 596.979 us; speedup vs baseline: 1.3498x; 1.2655x over previous
//
#include <hip/hip_runtime.h>
#include <hip/hip_bf16.h>

typedef _Float16 f16x8 __attribute__((ext_vector_type(8)));
typedef float f32x4  __attribute__((ext_vector_type(4)));

#define T_STEPS 40
#define BATCH   256
#define S2LO    0.000244140625f   // 2^-12, exact

__device__ __forceinline__ unsigned short f2h_bits(float f) {
    union { _Float16 h; unsigned short u; } c; c.h = (_Float16)f; return c.u;
}

// norse LIF step, pinned to mul-then-add fp32 order.
__device__ __forceinline__ float lif_update(float inp, float& v, float& i, float vth) {
    float vd = __fadd_rn(v, __fmul_rn(0.1f, __fsub_rn(i, v)));
    float id = __fmul_rn(0.8f, i);
    float z  = (vd > vth) ? 1.0f : 0.0f;
    v = (vd > vth) ? 0.0f : vd;
    i = __fadd_rn(id, inp);
    return z;
}

__device__ __forceinline__ void llds16(const unsigned short* g, void* l) {
    __builtin_amdgcn_global_load_lds(
        (const __attribute__((address_space(1))) unsigned int*)g,
        (__attribute__((address_space(3))) unsigned int*)l, 16, 0, 0);
}

// ---------------------------------------------------------------------------
// Kernel 1: conv1 (fp32) + LIF0 + 2x2 avgpool, persistent over t.
// Output s0 as fp16 (pooled quarters exact) [pos(169)][ic(24 pad)].
// ---------------------------------------------------------------------------
__global__ __launch_bounds__(576) void k_conv1(
    const float* __restrict__ x,             // [T,B,784] fp32
    const float* __restrict__ w1,            // [20,1,3,3] fp32
    unsigned short* __restrict__ s0)         // [T,B,169,24] fp16
{
    const int b   = blockIdx.x;
    const int tid = threadIdx.x;
    const bool active = tid < 520;
    const int oc = tid % 20;
    const int pr = tid / 20;

    __shared__ __align__(16) float xl[784];
    __shared__ __align__(16) float zl[20*26*26];

    float wr[9];
    if (active) {
        #pragma unroll
        for (int j = 0; j < 9; ++j) wr[j] = w1[oc*9 + j];
    }
    float vs[26], is[26];
    #pragma unroll
    for (int p = 0; p < 26; ++p) { vs[p] = 0.f; is[p] = 0.f; }

    for (int t = 0; t < T_STEPS; ++t) {
        const float* xs = x + (size_t)(t*BATCH + b)*784;
        for (int idx = tid; idx < 784; idx += 576) xl[idx] = xs[idx];
        __syncthreads();
        if (active) {
            float acc[26];
            #pragma unroll
            for (int p = 0; p < 26; ++p) acc[p] = 0.f;
            #pragma unroll
            for (int kr = 0; kr < 3; ++kr) {
                float row[28];
                #pragma unroll
                for (int q = 0; q < 7; ++q)
                    *(float4*)&row[q*4] = *(const float4*)&xl[(pr+kr)*28 + q*4];
                #pragma unroll
                for (int kc = 0; kc < 3; ++kc) {
                    float w = wr[kr*3+kc];
                    #pragma unroll
                    for (int p = 0; p < 26; ++p) acc[p] += row[p+kc] * w;
                }
            }
            #pragma unroll
            for (int p = 0; p < 26; ++p) {
                float z = lif_update(acc[p], vs[p], is[p], 0.2f);
                zl[(oc*26 + pr)*26 + p] = z;
            }
        }
        __syncthreads();
        size_t base = (size_t)(t*BATCH + b) * 4056;  // 169*24
        if (active && pr < 13) {
            #pragma unroll
            for (int q = 0; q < 13; ++q) {
                float s = zl[(oc*26 + 2*pr)*26 + 2*q]     + zl[(oc*26 + 2*pr)*26 + 2*q + 1]
                        + zl[(oc*26 + 2*pr + 1)*26 + 2*q] + zl[(oc*26 + 2*pr + 1)*26 + 2*q + 1];
                s0[base + (size_t)(pr*13 + q)*24 + oc] = f2h_bits(0.25f * s);
            }
        }
        for (int s2 = tid; s2 < 676; s2 += 576)
            s0[base + (size_t)(s2 >> 2)*24 + 20 + (s2 & 3)] = 0;
        __syncthreads();
    }
}

// ---------------------------------------------------------------------------
// Kernel 2: conv2 via fp16 MFMA, 2-plane weights (hi persistent in VGPR,
// scaled-lo from LDS; combine hi + 2^-12*lo) + LIF1. Waves 2m x 2n.
// ---------------------------------------------------------------------------
__global__ __launch_bounds__(256, 1) void k_conv2(
    const unsigned short* __restrict__ s0,   // [T,B,169,24] fp16
    const float* __restrict__ w2,            // [50,20,3,3] fp32
    unsigned short* __restrict__ z1)         // [T,B,6080] fp16 spikes
{
    const int b    = blockIdx.x;
    const int tid  = threadIdx.x;
    const int wv   = tid >> 6;
    const int lane = tid & 63;
    const int l15  = lane & 15;
    const int kg   = lane >> 4;
    const int wm   = wv & 1;
    const int wn   = wv >> 1;

    __shared__ __align__(16) unsigned short w2h[64*232];
    __shared__ __align__(16) unsigned short w2m[64*232];
    __shared__ __align__(16) unsigned short sIn[200*24];   // rows 169..199 zeroed

    for (int s = tid; s < 64*232; s += 256) {
        int ocw = s / 232, kk = s % 232;
        int g = kk / 24, ic = kk % 24;
        float val = 0.f;
        if (ocw < 50 && g < 9 && ic < 20) val = w2[(ocw*20 + ic)*9 + g];
        _Float16 h = (_Float16)val;
        float r1 = (val - (float)h) * 4096.0f;
        union { _Float16 h; unsigned short u; } ch, cm;
        ch.h = h; cm.h = (_Float16)r1;
        w2h[s] = ch.u;
        w2m[s] = cm.u;
    }
    for (int s = tid + 4056; s < 4800; s += 256) sIn[s] = 0;
    __syncthreads();

    f16x8 bfrH[2][7];
    #pragma unroll
    for (int nt = 0; nt < 2; ++nt) {
        int n = (wn*2 + nt)*16 + l15;
        #pragma unroll
        for (int kt = 0; kt < 7; ++kt)
            bfrH[nt][kt] = *(const f16x8*)&w2h[n*232 + kt*32 + kg*8];
    }

    int addrA[4][7];
    #pragma unroll
    for (int mt = 0; mt < 4; ++mt) {
        int pos = (wm*4 + mt)*16 + l15;
        #pragma unroll
        for (int kt = 0; kt < 7; ++kt) {
            int k = kt*32 + kg*8;
            int g = k / 24, o = k - g*24;
            if (pos <= 120 && g <= 8) {
                int in_idx = pos + 2*(pos/11) + 13*(g/3) + (g % 3);
                addrA[mt][kt] = in_idx*48 + o*2;
            } else addrA[mt][kt] = 180*48;   // zeroed row
        }
    }

    float vst[4][2][4], ist[4][2][4];
    #pragma unroll
    for (int mt = 0; mt < 4; ++mt)
        #pragma unroll
        for (int nt = 0; nt < 2; ++nt)
            #pragma unroll
            for (int r = 0; r < 4; ++r) { vst[mt][nt][r] = 0.f; ist[mt][nt][r] = 0.f; }

    const char* sInB = (const char*)sIn;
    const f32x4 zero4 = {0.f, 0.f, 0.f, 0.f};

    for (int t = 0; t < T_STEPS; ++t) {
        const unsigned int* src = (const unsigned int*)(s0 + (size_t)(t*BATCH + b)*4056);
        unsigned int* dst = (unsigned int*)sIn;
        for (int idx = tid; idx < 2028; idx += 256) dst[idx] = src[idx];
        __syncthreads();

        f32x4 acch[4][2], accl[4][2];
        #pragma unroll
        for (int mt = 0; mt < 4; ++mt)
            #pragma unroll
            for (int nt = 0; nt < 2; ++nt) { acch[mt][nt] = zero4; accl[mt][nt] = zero4; }

        #pragma unroll
        for (int kt = 0; kt < 7; ++kt) {
            f16x8 bm[2];
            #pragma unroll
            for (int nt = 0; nt < 2; ++nt) {
                int n = (wn*2 + nt)*16 + l15, k = kt*32 + kg*8;
                bm[nt] = *(const f16x8*)&w2m[n*232 + k];
            }
            #pragma unroll
            for (int mt = 0; mt < 4; ++mt) {
                f16x8 a = *(const f16x8*)(sInB + addrA[mt][kt]);
                #pragma unroll
                for (int nt = 0; nt < 2; ++nt) {
                    acch[mt][nt] = __builtin_amdgcn_mfma_f32_16x16x32_f16(
                        a, bfrH[nt][kt], acch[mt][nt], 0, 0, 0);
                    accl[mt][nt] = __builtin_amdgcn_mfma_f32_16x16x32_f16(
                        a, bm[nt], accl[mt][nt], 0, 0, 0);
                }
            }
        }

        size_t rowoff = (size_t)(t*BATCH + b) * 6080;
        #pragma unroll
        for (int mt = 0; mt < 4; ++mt) {
            int posb = (wm*4 + mt)*16 + kg*4;
            #pragma unroll
            for (int nt = 0; nt < 2; ++nt) {
                int ocn = (wn*2 + nt)*16 + l15;
                #pragma unroll
                for (int r = 0; r < 4; ++r) {
                    float inp = __fadd_rn(acch[mt][nt][r], __fmul_rn(S2LO, accl[mt][nt][r]));
                    float z = lif_update(inp, vst[mt][nt][r], ist[mt][nt][r], 0.2f);
                    int pos = posb + r;
                    if (ocn < 50 && pos <= 120)
                        z1[rowoff + ocn*121 + pos] = (z > 0.5f) ? (unsigned short)0x3C00 : (unsigned short)0;
                }
            }
        }
        if (tid < 30) z1[rowoff + 6050 + tid] = 0;
        __syncthreads();
    }
}

// ---------------------------------------------------------------------------
// MFMA GEMM (fp16), m97 2-buffer, global_load_lds w16, XOR-swizzled LDS
// (kills the 16-way bank conflicts). blockIdx.z selects weight plane.
// ---------------------------------------------------------------------------
__global__ __launch_bounds__(256, 3) void k_gemm(
    const unsigned short* __restrict__ A,
    const unsigned short* __restrict__ B0,
    float* __restrict__ C0,
    int Kp, int kiters, int ldc, int nstore,
    size_t strideB, size_t strideC)
{
    __shared__ __align__(16) unsigned short As[128*64];
    __shared__ __align__(16) unsigned short Bs[128*64];
    const unsigned short* B = B0 + (size_t)blockIdx.z * strideB;
    float* C = C0 + (size_t)blockIdx.z * strideC;

    const int tid  = threadIdx.x;
    const int lane = tid & 63;
    const int wv   = tid >> 6;
    const int wm   = wv & 1, wn = wv >> 1;
    const int l15  = lane & 15, kg = lane >> 4;
    const int mbase = blockIdx.x * 128;
    const int nbase = blockIdx.y * 128;

    const f32x4 zero4 = {0.f, 0.f, 0.f, 0.f};
    f32x4 acc[4][4];
    #pragma unroll
    for (int mt = 0; mt < 4; ++mt)
        #pragma unroll
        for (int nt = 0; nt < 4; ++nt) acc[mt][nt] = zero4;

    const int rowA = tid >> 3;                        // 0..31
    const int sw   = (((tid & 7) ^ (rowA & 7))) * 8;  // xor-swizzled chunk (elems)
    char* ldsA = (char*)As + (size_t)wv*1024;
    char* ldsB = (char*)Bs + (size_t)wv*1024;

    for (int ki = 0; ki < kiters; ++ki) {
        int kb = ki * 64;
        #pragma unroll
        for (int c = 0; c < 4; ++c) {
            int row = c*32 + rowA;
            llds16(A + (size_t)(mbase + row)*Kp + kb + sw, ldsA + c*4096);
            llds16(B + (size_t)(nbase + row)*Kp + kb + sw, ldsB + c*4096);
        }
        __syncthreads();
        #pragma unroll
        for (int kt = 0; kt < 2; ++kt) {
            f16x8 bfv[4], afv[4];
            #pragma unroll
            for (int nt = 0; nt < 4; ++nt) {
                int rb = wn*64 + nt*16 + l15;
                int ch = ((kt*4 + kg) ^ (rb & 7)) * 8;
                bfv[nt] = *(const f16x8*)&Bs[rb*64 + ch];
            }
            #pragma unroll
            for (int mt = 0; mt < 4; ++mt) {
                int ra = wm*64 + mt*16 + l15;
                int ch = ((kt*4 + kg) ^ (ra & 7)) * 8;
                afv[mt] = *(const f16x8*)&As[ra*64 + ch];
            }
            #pragma unroll
            for (int mt = 0; mt < 4; ++mt)
                #pragma unroll
                for (int nt = 0; nt < 4; ++nt)
                    acc[mt][nt] = __builtin_amdgcn_mfma_f32_16x16x32_f16(
                        afv[mt], bfv[nt], acc[mt][nt], 0, 0, 0);
        }
        __syncthreads();
    }

    #pragma unroll
    for (int mt = 0; mt < 4; ++mt) {
        int m0 = mbase + wm*64 + mt*16 + kg*4;
        #pragma unroll
        for (int nt = 0; nt < 4; ++nt) {
            int n = nbase + wn*64 + nt*16 + l15;
            if (n < nstore) {
                #pragma unroll
                for (int r = 0; r < 4; ++r)
                    C[(size_t)(m0 + r)*ldc + n] = acc[mt][nt][r];
            }
        }
    }
}

// Pack fp32 weights [N,K] -> zero-padded fp16 planes: hi = fp16(w),
// lo = fp16((w - hi) * 2^12)  (scaled to stay normal in fp16)
__global__ void k_pack(const float* __restrict__ src,
                       unsigned short* __restrict__ hi, unsigned short* __restrict__ lo,
                       int N, int K, int Kp, int total) {
    int idx = blockIdx.x*256 + threadIdx.x;
    if (idx >= total) return;
    int n = idx / Kp, k = idx - n*Kp;
    float v = (n < N && k < K) ? src[n*K + k] : 0.f;
    _Float16 h = (_Float16)v;
    float r1 = (v - (float)h) * 4096.0f;
    union { _Float16 h; unsigned short u; } ch, cl;
    ch.h = h; cl.h = (_Float16)r1;
    hi[idx] = ch.u;
    lo[idx] = cl.u;
}

// LIF scan over t for fc layers: s = hi_dot + 2^-12 * lo_dot, LIF recurrence.
__global__ __launch_bounds__(512) void k_lif_scan(
    const float* __restrict__ c0, size_t pstride,
    unsigned short* __restrict__ zout,
    int ld, int nvalid, float vth)
{
    int b = blockIdx.x;
    int n = threadIdx.x;
    float v = 0.f, cur = 0.f;
    for (int t = 0; t < T_STEPS; ++t) {
        size_t idx = (size_t)(t*BATCH + b)*ld + n;
        float s = __fadd_rn(c0[idx], __fmul_rn(S2LO, c0[idx + pstride]));
        float z = lif_update(s, v, cur, vth);
        zout[idx] = (n < nvalid && z > 0.5f) ? (unsigned short)0x3C00 : (unsigned short)0;
    }
}

// LI output cell scan: s = hi + 2^-12*lo; out[t] = decayed membrane (fp32)
__global__ void k_li(const float* __restrict__ c0, size_t pstride, float* __restrict__ out) {
    int g = blockIdx.x*64 + threadIdx.x;
    if (g >= 2560) return;
    int b = g / 10, n = g - b*10;
    float vo = 0.f, io = 0.f;
    for (int t = 0; t < T_STEPS; ++t) {
        size_t idx = (size_t)(t*BATCH + b)*16 + n;
        float s = __fadd_rn(c0[idx], __fmul_rn(S2LO, c0[idx + pstride]));
        float vd = __fadd_rn(vo, __fmul_rn(0.1f, __fsub_rn(io, vo)));
        out[(size_t)(t*BATCH + b)*10 + n] = vd;
        io = __fadd_rn(__fmul_rn(0.8f, io), s);
        vo = vd;
    }
}

extern "C" void kernel_launch(void* const* d_in, const int* in_sizes, int n_in,
                              void* d_out, int out_size, void* d_ws, size_t ws_size,
                              hipStream_t stream) {
    (void)in_sizes; (void)n_in; (void)out_size; (void)ws_size;
    const float* x   = (const float*)d_in[0];
    const float* w1  = (const float*)d_in[1];
    const float* w2  = (const float*)d_in[2];
    const float* wf1 = (const float*)d_in[3];
    const float* wf2 = (const float*)d_in[4];
    const float* wfo = (const float*)d_in[5];
    char* ws = (char*)d_ws;

    // ---- workspace layout (footprint <= 207,585,280 B, proven safe) ----
    // phase A (conv): z1 @0 [0,124.5M), s0 @124,518,400
    // phase B (fc1):  z1 live; 2-plane W + c2p overlay dead s0:
    //   W1 [124,518,400, 136,970,240)   2 x [512][6080] fp16
    //   W2 [136,970,240, 137,494,528)   2 x [256][512]
    //   Wo [137,494,528, 137,625,600)   2 x [128][256]
    //   c2p[137,625,600, 179,568,640)   2 x [10240][512] fp32
    // phase C (fc2+): z1 dead; low region, all disjoint:
    //   z2  [0, 10,485,760)
    //   c3p [10,485,760, 31,457,280)    2 x [10240][256] fp32
    //   z3  [31,457,280, 36,700,160)
    //   c4p [36,700,160, 38,010,880)    2 x [10240][16] fp32
    unsigned short* z1    = (unsigned short*)(ws);
    unsigned short* s0    = (unsigned short*)(ws + 124518400);
    unsigned short* W1hi  = (unsigned short*)(ws + 124518400);
    unsigned short* W2hi  = (unsigned short*)(ws + 136970240);
    unsigned short* Wohi  = (unsigned short*)(ws + 137494528);
    float*          c2p   = (float*)(ws + 137625600);
    unsigned short* z2    = (unsigned short*)(ws);
    float*          c3p   = (float*)(ws + 10485760);
    unsigned short* z3    = (unsigned short*)(ws + 31457280);
    float*          c4p   = (float*)(ws + 36700160);

    k_conv1<<<256, 576, 0, stream>>>(x, w1, s0);
    k_conv2<<<256, 256, 0, stream>>>(s0, w2, z1);

    k_pack<<<(3112960+255)/256, 256, 0, stream>>>(wf1, W1hi, W1hi+3112960, 500, 6050, 6080, 3112960);
    k_pack<<<(131072+255)/256,  256, 0, stream>>>(wf2, W2hi, W2hi+131072,  200, 500,  512,  131072);
    k_pack<<<(32768+255)/256,   256, 0, stream>>>(wfo, Wohi, Wohi+32768,   10,  200,  256,  32768);

    k_gemm<<<dim3(80,4,2), 256, 0, stream>>>(z1, W1hi, c2p, 6080, 95, 512, 512,
                                             (size_t)3112960, (size_t)5242880);
    k_lif_scan<<<256, 512, 0, stream>>>(c2p, (size_t)5242880, z2, 512, 500, 0.1f);
    k_gemm<<<dim3(80,2,2), 256, 0, stream>>>(z2, W2hi, c3p, 512, 8, 256, 256,
                                             (size_t)131072, (size_t)2621440);
    k_lif_scan<<<256, 256, 0, stream>>>(c3p, (size_t)2621440, z3, 256, 200, 0.05f);
    k_gemm<<<dim3(80,1,2), 256, 0, stream>>>(z3, Wohi, c4p, 256, 4, 16, 16,
                                             (size_t)32768, (size_t)163840);
    k_li<<<40, 64, 0, stream>>>(c4p, (size_t)163840, (float*)d_out);
}

// Round 8
// 531.155 us; speedup vs baseline: 1.5171x; 1.1239x over previous
//
#include <hip/hip_runtime.h>
#include <hip/hip_bf16.h>

typedef _Float16 f16x8 __attribute__((ext_vector_type(8)));
typedef float f32x4  __attribute__((ext_vector_type(4)));

#define T_STEPS 40
#define BATCH   256
#define S2LO    0.000244140625f   // 2^-12, exact

__device__ __forceinline__ unsigned short f2h_bits(float f) {
    union { _Float16 h; unsigned short u; } c; c.h = (_Float16)f; return c.u;
}

// norse LIF step, pinned to mul-then-add fp32 order.
__device__ __forceinline__ float lif_update(float inp, float& v, float& i, float vth) {
    float vd = __fadd_rn(v, __fmul_rn(0.1f, __fsub_rn(i, v)));
    float id = __fmul_rn(0.8f, i);
    float z  = (vd > vth) ? 1.0f : 0.0f;
    v = (vd > vth) ? 0.0f : vd;
    i = __fadd_rn(id, inp);
    return z;
}

__device__ __forceinline__ void llds16(const unsigned short* g, void* l) {
    __builtin_amdgcn_global_load_lds(
        (const __attribute__((address_space(1))) unsigned int*)g,
        (__attribute__((address_space(3))) unsigned int*)l, 16, 0, 0);
}

// ---------------------------------------------------------------------------
// Kernel 1: conv1 (fp32) + LIF0 + 2x2 avgpool, persistent over t.
// Output s0 fp16, row stride 4096 elems (8192 B): [pos169][ic24] + zero tail.
// ---------------------------------------------------------------------------
__global__ __launch_bounds__(576) void k_conv1(
    const float* __restrict__ x,             // [T,B,784] fp32
    const float* __restrict__ w1,            // [20,1,3,3] fp32
    unsigned short* __restrict__ s0)         // [T,B,4096] fp16
{
    const int b   = blockIdx.x;
    const int tid = threadIdx.x;
    const bool active = tid < 520;
    const int oc = tid % 20;
    const int pr = tid / 20;

    __shared__ __align__(16) float xl[784];
    __shared__ __align__(16) float zl[20*26*26];

    float wr[9];
    if (active) {
        #pragma unroll
        for (int j = 0; j < 9; ++j) wr[j] = w1[oc*9 + j];
    }
    float vs[26], is[26];
    #pragma unroll
    for (int p = 0; p < 26; ++p) { vs[p] = 0.f; is[p] = 0.f; }

    for (int t = 0; t < T_STEPS; ++t) {
        const float* xs = x + (size_t)(t*BATCH + b)*784;
        for (int idx = tid; idx < 784; idx += 576) xl[idx] = xs[idx];
        __syncthreads();
        if (active) {
            float acc[26];
            #pragma unroll
            for (int p = 0; p < 26; ++p) acc[p] = 0.f;
            #pragma unroll
            for (int kr = 0; kr < 3; ++kr) {
                float row[28];
                #pragma unroll
                for (int q = 0; q < 7; ++q)
                    *(float4*)&row[q*4] = *(const float4*)&xl[(pr+kr)*28 + q*4];
                #pragma unroll
                for (int kc = 0; kc < 3; ++kc) {
                    float w = wr[kr*3+kc];
                    #pragma unroll
                    for (int p = 0; p < 26; ++p) acc[p] += row[p+kc] * w;
                }
            }
            #pragma unroll
            for (int p = 0; p < 26; ++p) {
                float z = lif_update(acc[p], vs[p], is[p], 0.2f);
                zl[(oc*26 + pr)*26 + p] = z;
            }
        }
        __syncthreads();
        size_t base = (size_t)(t*BATCH + b) * 4096;
        if (active && pr < 13) {
            #pragma unroll
            for (int q = 0; q < 13; ++q) {
                float s = zl[(oc*26 + 2*pr)*26 + 2*q]     + zl[(oc*26 + 2*pr)*26 + 2*q + 1]
                        + zl[(oc*26 + 2*pr + 1)*26 + 2*q] + zl[(oc*26 + 2*pr + 1)*26 + 2*q + 1];
                s0[base + (size_t)(pr*13 + q)*24 + oc] = f2h_bits(0.25f * s);
            }
        }
        for (int s2 = tid; s2 < 716; s2 += 576) {
            if (s2 < 676) s0[base + (size_t)(s2 >> 2)*24 + 20 + (s2 & 3)] = 0;  // ic pad
            else          s0[base + 4056 + (s2 - 676)] = 0;                     // row tail
        }
        __syncthreads();
    }
}

// ---------------------------------------------------------------------------
// Kernel 2: conv2 via fp16 MFMA, 2 blocks/sample (oc-split), double-buffered
// async staging (global_load_lds), one barrier per step. 2-plane weights
// (hi persistent in VGPR, scaled-lo from LDS) + LIF1 states in VGPRs.
// Waves: wm=wv covers 32 pos (mt=2); nt=2 covers 32 oc (this block's half).
// ---------------------------------------------------------------------------
__global__ __launch_bounds__(256, 2) void k_conv2(
    const unsigned short* __restrict__ s0,   // [T,B,4096] fp16
    const float* __restrict__ w2,            // [50,20,3,3] fp32
    unsigned short* __restrict__ z1)         // [T,B,6080] fp16 spikes
{
    const int b    = blockIdx.x >> 1;
    const int half = blockIdx.x & 1;
    const int tid  = threadIdx.x;
    const int wv   = tid >> 6;
    const int lane = tid & 63;
    const int l15  = lane & 15;
    const int kg   = lane >> 4;
    const int wm   = wv;           // 4 m-waves x 32 pos

    __shared__ __align__(16) unsigned short w2h[32*232];
    __shared__ __align__(16) unsigned short w2m[32*232];
    __shared__ __align__(16) unsigned short sIn[2*4096];   // double buffer

    for (int s = tid; s < 32*232; s += 256) {
        int ocw = s / 232, kk = s % 232;
        int g = kk / 24, ic = kk % 24;
        int oc = half*32 + ocw;
        float val = 0.f;
        if (oc < 50 && g < 9 && ic < 20) val = w2[(oc*20 + ic)*9 + g];
        _Float16 h = (_Float16)val;
        float r1 = (val - (float)h) * 4096.0f;
        union { _Float16 h; unsigned short u; } ch, cm;
        ch.h = h; cm.h = (_Float16)r1;
        w2h[s] = ch.u;
        w2m[s] = cm.u;
    }
    __syncthreads();

    f16x8 bfrH[2][7];
    #pragma unroll
    for (int nt = 0; nt < 2; ++nt) {
        int n = nt*16 + l15;
        #pragma unroll
        for (int kt = 0; kt < 7; ++kt)
            bfrH[nt][kt] = *(const f16x8*)&w2h[n*232 + kt*32 + kg*8];
    }

    int addrA[2][7];
    #pragma unroll
    for (int mt = 0; mt < 2; ++mt) {
        int pos = wm*32 + mt*16 + l15;
        #pragma unroll
        for (int kt = 0; kt < 7; ++kt) {
            int k = kt*32 + kg*8;
            int g = k / 24, o = k - g*24;
            if (pos <= 120 && g <= 8) {
                int in_idx = pos + 2*(pos/11) + 13*(g/3) + (g % 3);
                addrA[mt][kt] = in_idx*48 + o*2;
            } else addrA[mt][kt] = 8128;   // zero tail of the 8192-B buffer
        }
    }

    float vst[2][2][4], ist[2][2][4];
    #pragma unroll
    for (int mt = 0; mt < 2; ++mt)
        #pragma unroll
        for (int nt = 0; nt < 2; ++nt)
            #pragma unroll
            for (int r = 0; r < 4; ++r) { vst[mt][nt][r] = 0.f; ist[mt][nt][r] = 0.f; }

    const f32x4 zero4 = {0.f, 0.f, 0.f, 0.f};

    // prologue: stage t=0 into buffer 0
    {
        const unsigned short* srow = s0 + (size_t)(0*BATCH + b)*4096;
        char* nb = (char*)sIn + (size_t)wv*1024;
        llds16(srow + tid*8, nb);
        llds16(srow + 2048 + tid*8, nb + 4096);
    }

    for (int t = 0; t < T_STEPS; ++t) {
        __syncthreads();   // drains staging of t (and frees buffer (t+1)&1)
        if (t + 1 < T_STEPS) {
            const unsigned short* srow = s0 + (size_t)((t+1)*BATCH + b)*4096;
            char* nb = (char*)sIn + ((t+1)&1)*8192 + (size_t)wv*1024;
            llds16(srow + tid*8, nb);
            llds16(srow + 2048 + tid*8, nb + 4096);
        }
        const char* curB = (const char*)sIn + (t&1)*8192;

        f32x4 acch[2][2], accl[2][2];
        #pragma unroll
        for (int mt = 0; mt < 2; ++mt)
            #pragma unroll
            for (int nt = 0; nt < 2; ++nt) { acch[mt][nt] = zero4; accl[mt][nt] = zero4; }

        #pragma unroll
        for (int kt = 0; kt < 7; ++kt) {
            f16x8 bm[2];
            #pragma unroll
            for (int nt = 0; nt < 2; ++nt) {
                int n = nt*16 + l15, k = kt*32 + kg*8;
                bm[nt] = *(const f16x8*)&w2m[n*232 + k];
            }
            #pragma unroll
            for (int mt = 0; mt < 2; ++mt) {
                f16x8 a = *(const f16x8*)(curB + addrA[mt][kt]);
                #pragma unroll
                for (int nt = 0; nt < 2; ++nt) {
                    acch[mt][nt] = __builtin_amdgcn_mfma_f32_16x16x32_f16(
                        a, bfrH[nt][kt], acch[mt][nt], 0, 0, 0);
                    accl[mt][nt] = __builtin_amdgcn_mfma_f32_16x16x32_f16(
                        a, bm[nt], accl[mt][nt], 0, 0, 0);
                }
            }
        }

        size_t rowoff = (size_t)(t*BATCH + b) * 6080;
        #pragma unroll
        for (int mt = 0; mt < 2; ++mt) {
            int posb = wm*32 + mt*16 + kg*4;
            #pragma unroll
            for (int nt = 0; nt < 2; ++nt) {
                int ocn = half*32 + nt*16 + l15;
                #pragma unroll
                for (int r = 0; r < 4; ++r) {
                    float inp = __fadd_rn(acch[mt][nt][r], __fmul_rn(S2LO, accl[mt][nt][r]));
                    float z = lif_update(inp, vst[mt][nt][r], ist[mt][nt][r], 0.2f);
                    int pos = posb + r;
                    if (ocn < 50 && pos <= 120)
                        z1[rowoff + ocn*121 + pos] = (z > 0.5f) ? (unsigned short)0x3C00 : (unsigned short)0;
                }
            }
        }
        if (half == 0 && tid < 30) z1[rowoff + 6050 + tid] = 0;
    }
}

// ---------------------------------------------------------------------------
// MFMA GEMM (fp16), m97 2-buffer, global_load_lds w16, XOR-swizzled LDS.
// blockIdx.z selects weight plane. 128x128 tile, BK=64.
// ---------------------------------------------------------------------------
__global__ __launch_bounds__(256, 3) void k_gemm(
    const unsigned short* __restrict__ A,
    const unsigned short* __restrict__ B0,
    float* __restrict__ C0,
    int Kp, int kiters, int ldc, int nstore,
    size_t strideB, size_t strideC)
{
    __shared__ __align__(16) unsigned short As[128*64];
    __shared__ __align__(16) unsigned short Bs[128*64];
    const unsigned short* B = B0 + (size_t)blockIdx.z * strideB;
    float* C = C0 + (size_t)blockIdx.z * strideC;

    const int tid  = threadIdx.x;
    const int lane = tid & 63;
    const int wv   = tid >> 6;
    const int wm   = wv & 1, wn = wv >> 1;
    const int l15  = lane & 15, kg = lane >> 4;
    const int mbase = blockIdx.x * 128;
    const int nbase = blockIdx.y * 128;

    const f32x4 zero4 = {0.f, 0.f, 0.f, 0.f};
    f32x4 acc[4][4];
    #pragma unroll
    for (int mt = 0; mt < 4; ++mt)
        #pragma unroll
        for (int nt = 0; nt < 4; ++nt) acc[mt][nt] = zero4;

    const int rowA = tid >> 3;                        // 0..31
    const int sw   = (((tid & 7) ^ (rowA & 7))) * 8;  // xor-swizzled chunk (elems)
    char* ldsA = (char*)As + (size_t)wv*1024;
    char* ldsB = (char*)Bs + (size_t)wv*1024;

    for (int ki = 0; ki < kiters; ++ki) {
        int kb = ki * 64;
        #pragma unroll
        for (int c = 0; c < 4; ++c) {
            int row = c*32 + rowA;
            llds16(A + (size_t)(mbase + row)*Kp + kb + sw, ldsA + c*4096);
            llds16(B + (size_t)(nbase + row)*Kp + kb + sw, ldsB + c*4096);
        }
        __syncthreads();
        #pragma unroll
        for (int kt = 0; kt < 2; ++kt) {
            f16x8 bfv[4], afv[4];
            #pragma unroll
            for (int nt = 0; nt < 4; ++nt) {
                int rb = wn*64 + nt*16 + l15;
                int ch = ((kt*4 + kg) ^ (rb & 7)) * 8;
                bfv[nt] = *(const f16x8*)&Bs[rb*64 + ch];
            }
            #pragma unroll
            for (int mt = 0; mt < 4; ++mt) {
                int ra = wm*64 + mt*16 + l15;
                int ch = ((kt*4 + kg) ^ (ra & 7)) * 8;
                afv[mt] = *(const f16x8*)&As[ra*64 + ch];
            }
            #pragma unroll
            for (int mt = 0; mt < 4; ++mt)
                #pragma unroll
                for (int nt = 0; nt < 4; ++nt)
                    acc[mt][nt] = __builtin_amdgcn_mfma_f32_16x16x32_f16(
                        afv[mt], bfv[nt], acc[mt][nt], 0, 0, 0);
        }
        __syncthreads();
    }

    #pragma unroll
    for (int mt = 0; mt < 4; ++mt) {
        int m0 = mbase + wm*64 + mt*16 + kg*4;
        #pragma unroll
        for (int nt = 0; nt < 4; ++nt) {
            int n = nbase + wn*64 + nt*16 + l15;
            if (n < nstore) {
                #pragma unroll
                for (int r = 0; r < 4; ++r)
                    C[(size_t)(m0 + r)*ldc + n] = acc[mt][nt][r];
            }
        }
    }
}

// Pack fp32 weights [N,K] -> zero-padded fp16 planes: hi = fp16(w),
// lo = fp16((w - hi) * 2^12)
__global__ void k_pack(const float* __restrict__ src,
                       unsigned short* __restrict__ hi, unsigned short* __restrict__ lo,
                       int N, int K, int Kp, int total) {
    int idx = blockIdx.x*256 + threadIdx.x;
    if (idx >= total) return;
    int n = idx / Kp, k = idx - n*Kp;
    float v = (n < N && k < K) ? src[n*K + k] : 0.f;
    _Float16 h = (_Float16)v;
    float r1 = (v - (float)h) * 4096.0f;
    union { _Float16 h; unsigned short u; } ch, cl;
    ch.h = h; cl.h = (_Float16)r1;
    hi[idx] = ch.u;
    lo[idx] = cl.u;
}

// LIF scan over t for fc layers: s = hi_dot + 2^-12 * lo_dot, LIF recurrence.
__global__ __launch_bounds__(512) void k_lif_scan(
    const float* __restrict__ c0, size_t pstride,
    unsigned short* __restrict__ zout,
    int ld, int nvalid, float vth)
{
    int b = blockIdx.x;
    int n = threadIdx.x;
    float v = 0.f, cur = 0.f;
    for (int t = 0; t < T_STEPS; ++t) {
        size_t idx = (size_t)(t*BATCH + b)*ld + n;
        float s = __fadd_rn(c0[idx], __fmul_rn(S2LO, c0[idx + pstride]));
        float z = lif_update(s, v, cur, vth);
        zout[idx] = (n < nvalid && z > 0.5f) ? (unsigned short)0x3C00 : (unsigned short)0;
    }
}

// LI output cell scan: s = hi + 2^-12*lo; out[t] = decayed membrane (fp32)
__global__ void k_li(const float* __restrict__ c0, size_t pstride, float* __restrict__ out) {
    int g = blockIdx.x*64 + threadIdx.x;
    if (g >= 2560) return;
    int b = g / 10, n = g - b*10;
    float vo = 0.f, io = 0.f;
    for (int t = 0; t < T_STEPS; ++t) {
        size_t idx = (size_t)(t*BATCH + b)*16 + n;
        float s = __fadd_rn(c0[idx], __fmul_rn(S2LO, c0[idx + pstride]));
        float vd = __fadd_rn(vo, __fmul_rn(0.1f, __fsub_rn(io, vo)));
        out[(size_t)(t*BATCH + b)*10 + n] = vd;
        io = __fadd_rn(__fmul_rn(0.8f, io), s);
        vo = vd;
    }
}

extern "C" void kernel_launch(void* const* d_in, const int* in_sizes, int n_in,
                              void* d_out, int out_size, void* d_ws, size_t ws_size,
                              hipStream_t stream) {
    (void)in_sizes; (void)n_in; (void)out_size; (void)ws_size;
    const float* x   = (const float*)d_in[0];
    const float* w1  = (const float*)d_in[1];
    const float* w2  = (const float*)d_in[2];
    const float* wf1 = (const float*)d_in[3];
    const float* wf2 = (const float*)d_in[4];
    const float* wfo = (const float*)d_in[5];
    char* ws = (char*)d_ws;

    // ---- workspace layout ----
    // phase A (conv): z1 [0, 124,518,400); s0 [124,518,400, 208,404,480)
    //                 (10240 x 4096 fp16; region up to ~214 MB proven writable r3)
    // phase B (fc1):  z1 live; 2-plane W + c2p overlay dead s0:
    //   W1 [124,518,400, 136,970,240)   2 x [512][6080] fp16
    //   W2 [136,970,240, 137,494,528)   2 x [256][512]
    //   Wo [137,494,528, 137,625,600)   2 x [128][256]
    //   c2p[137,625,600, 179,568,640)   2 x [10240][512] fp32
    // phase C (fc2+): z1 dead; low region, disjoint:
    //   z2 [0, 10,485,760) ; c3p [10,485,760, 31,457,280) ;
    //   z3 [31,457,280, 36,700,160) ; c4p [36,700,160, 38,010,880)
    unsigned short* z1    = (unsigned short*)(ws);
    unsigned short* s0    = (unsigned short*)(ws + 124518400);
    unsigned short* W1hi  = (unsigned short*)(ws + 124518400);
    unsigned short* W2hi  = (unsigned short*)(ws + 136970240);
    unsigned short* Wohi  = (unsigned short*)(ws + 137494528);
    float*          c2p   = (float*)(ws + 137625600);
    unsigned short* z2    = (unsigned short*)(ws);
    float*          c3p   = (float*)(ws + 10485760);
    unsigned short* z3    = (unsigned short*)(ws + 31457280);
    float*          c4p   = (float*)(ws + 36700160);

    k_conv1<<<256, 576, 0, stream>>>(x, w1, s0);
    k_conv2<<<512, 256, 0, stream>>>(s0, w2, z1);

    k_pack<<<(3112960+255)/256, 256, 0, stream>>>(wf1, W1hi, W1hi+3112960, 500, 6050, 6080, 3112960);
    k_pack<<<(131072+255)/256,  256, 0, stream>>>(wf2, W2hi, W2hi+131072,  200, 500,  512,  131072);
    k_pack<<<(32768+255)/256,   256, 0, stream>>>(wfo, Wohi, Wohi+32768,   10,  200,  256,  32768);

    k_gemm<<<dim3(80,4,2), 256, 0, stream>>>(z1, W1hi, c2p, 6080, 95, 512, 512,
                                             (size_t)3112960, (size_t)5242880);
    k_lif_scan<<<256, 512, 0, stream>>>(c2p, (size_t)5242880, z2, 512, 500, 0.1f);
    k_gemm<<<dim3(80,2,2), 256, 0, stream>>>(z2, W2hi, c3p, 512, 8, 256, 256,
                                             (size_t)131072, (size_t)2621440);
    k_lif_scan<<<256, 256, 0, stream>>>(c3p, (size_t)2621440, z3, 256, 200, 0.05f);
    k_gemm<<<dim3(80,1,2), 256, 0, stream>>>(z3, Wohi, c4p, 256, 4, 16, 16,
                                             (size_t)32768, (size_t)163840);
    k_li<<<40, 64, 0, stream>>>(c4p, (size_t)163840, (float*)d_out);
}

// Round 9
// 451.579 us; speedup vs baseline: 1.7844x; 1.1762x over previous
//
#include <hip/hip_runtime.h>
#include <hip/hip_bf16.h>

typedef _Float16 f16x8 __attribute__((ext_vector_type(8)));
typedef float f32x4  __attribute__((ext_vector_type(4)));
typedef unsigned short u16x4 __attribute__((ext_vector_type(4)));

#define T_STEPS 40
#define BATCH   256
#define S2LO    0.000244140625f   // 2^-12, exact

__device__ __forceinline__ unsigned short f2h_bits(float f) {
    union { _Float16 h; unsigned short u; } c; c.h = (_Float16)f; return c.u;
}

// norse LIF step, pinned to mul-then-add fp32 order.
__device__ __forceinline__ float lif_update(float inp, float& v, float& i, float vth) {
    float vd = __fadd_rn(v, __fmul_rn(0.1f, __fsub_rn(i, v)));
    float id = __fmul_rn(0.8f, i);
    float z  = (vd > vth) ? 1.0f : 0.0f;
    v = (vd > vth) ? 0.0f : vd;
    i = __fadd_rn(id, inp);
    return z;
}

__device__ __forceinline__ void llds16(const unsigned short* g, void* l) {
    __builtin_amdgcn_global_load_lds(
        (const __attribute__((address_space(1))) unsigned int*)g,
        (__attribute__((address_space(3))) unsigned int*)l, 16, 0, 0);
}

// ---------------------------------------------------------------------------
// Kernel 1: conv1 (fp32) + LIF0 + 2x2 avgpool, persistent over t.
// Output s0 as u8 (pooled sum 0..4; exact), row stride 4096: [pos169][ic24]+pad.
// ---------------------------------------------------------------------------
__global__ __launch_bounds__(576) void k_conv1(
    const float* __restrict__ x,             // [T,B,784] fp32
    const float* __restrict__ w1,            // [20,1,3,3] fp32
    unsigned char* __restrict__ s0)          // [T,B,4096] u8
{
    const int b   = blockIdx.x;
    const int tid = threadIdx.x;
    const bool active = tid < 520;
    const int oc = tid % 20;
    const int pr = tid / 20;

    __shared__ __align__(16) float xl[784];
    __shared__ __align__(16) float zl[20*26*26];

    float wr[9];
    if (active) {
        #pragma unroll
        for (int j = 0; j < 9; ++j) wr[j] = w1[oc*9 + j];
    }
    float vs[26], is[26];
    #pragma unroll
    for (int p = 0; p < 26; ++p) { vs[p] = 0.f; is[p] = 0.f; }

    for (int t = 0; t < T_STEPS; ++t) {
        const float* xs = x + (size_t)(t*BATCH + b)*784;
        for (int idx = tid; idx < 784; idx += 576) xl[idx] = xs[idx];
        __syncthreads();
        if (active) {
            float acc[26];
            #pragma unroll
            for (int p = 0; p < 26; ++p) acc[p] = 0.f;
            #pragma unroll
            for (int kr = 0; kr < 3; ++kr) {
                float row[28];
                #pragma unroll
                for (int q = 0; q < 7; ++q)
                    *(float4*)&row[q*4] = *(const float4*)&xl[(pr+kr)*28 + q*4];
                #pragma unroll
                for (int kc = 0; kc < 3; ++kc) {
                    float w = wr[kr*3+kc];
                    #pragma unroll
                    for (int p = 0; p < 26; ++p) acc[p] += row[p+kc] * w;
                }
            }
            #pragma unroll
            for (int p = 0; p < 26; ++p) {
                float z = lif_update(acc[p], vs[p], is[p], 0.2f);
                zl[(oc*26 + pr)*26 + p] = z;
            }
        }
        __syncthreads();
        size_t base = (size_t)(t*BATCH + b) * 4096;
        if (active && pr < 13) {
            #pragma unroll
            for (int q = 0; q < 13; ++q) {
                float s = zl[(oc*26 + 2*pr)*26 + 2*q]     + zl[(oc*26 + 2*pr)*26 + 2*q + 1]
                        + zl[(oc*26 + 2*pr + 1)*26 + 2*q] + zl[(oc*26 + 2*pr + 1)*26 + 2*q + 1];
                s0[base + (size_t)(pr*13 + q)*24 + oc] = (unsigned char)s;
            }
        }
        for (int s2 = tid; s2 < 716; s2 += 576) {
            if (s2 < 676) s0[base + (size_t)(s2 >> 2)*24 + 20 + (s2 & 3)] = 0;  // ic pad
            else          s0[base + 4056 + (s2 - 676)] = 0;                     // row tail
        }
        __syncthreads();
    }
}

// ---------------------------------------------------------------------------
// Kernel 2: conv2 via fp16 MFMA, 2 blocks/sample (oc-split), double-buffered
// staging (u8 global->regs->fp16->ds_write_b128), one barrier/step. 2-plane
// weights (hi persistent in VGPR, scaled-lo from LDS) + LIF1 in VGPRs.
// z1 layout: oc-stride 124 -> aligned ushort4 stores (4 instrs/step, was 16).
// ---------------------------------------------------------------------------
__global__ __launch_bounds__(256, 2) void k_conv2(
    const unsigned char* __restrict__ s0,    // [T,B,4096] u8
    const float* __restrict__ w2,            // [50,20,3,3] fp32
    unsigned short* __restrict__ z1)         // [T,B,6208] fp16 spikes
{
    const int b    = blockIdx.x >> 1;
    const int half = blockIdx.x & 1;
    const int tid  = threadIdx.x;
    const int wv   = tid >> 6;
    const int lane = tid & 63;
    const int l15  = lane & 15;
    const int kg   = lane >> 4;
    const int wm   = wv;           // 4 m-waves x 32 pos

    __shared__ __align__(16) unsigned short w2h[32*232];
    __shared__ __align__(16) unsigned short w2m[32*232];
    __shared__ __align__(16) unsigned short sIn[2*4096];   // fp16 double buffer

    for (int s = tid; s < 32*232; s += 256) {
        int ocw = s / 232, kk = s % 232;
        int g = kk / 24, ic = kk % 24;
        int oc = half*32 + ocw;
        float val = 0.f;
        if (oc < 50 && g < 9 && ic < 20) val = w2[(oc*20 + ic)*9 + g];
        _Float16 h = (_Float16)val;
        float r1 = (val - (float)h) * 4096.0f;
        union { _Float16 h; unsigned short u; } ch, cm;
        ch.h = h; cm.h = (_Float16)r1;
        w2h[s] = ch.u;
        w2m[s] = cm.u;
    }

    f16x8 bfrH[2][7];
    int addrA[2][7];
    #pragma unroll
    for (int mt = 0; mt < 2; ++mt) {
        int pos = wm*32 + mt*16 + l15;
        #pragma unroll
        for (int kt = 0; kt < 7; ++kt) {
            int k = kt*32 + kg*8;
            int g = k / 24, o = k - g*24;
            if (pos <= 120 && g <= 8) {
                int in_idx = pos + 2*(pos/11) + 13*(g/3) + (g % 3);
                addrA[mt][kt] = in_idx*48 + o*2;
            } else addrA[mt][kt] = 8128;   // elem 4064: inside zeroed tail (4056..4095)
        }
    }

    // stage t=0 into buffer 0 (u8 -> fp16*0.25, exact)
    {
        const unsigned char* srow = s0 + (size_t)(0*BATCH + b)*4096;
        uint4 raw = *(const uint4*)(srow + tid*16);
        unsigned short hv[16];
        #pragma unroll
        for (int w = 0; w < 4; ++w) {
            unsigned int u = ((const unsigned int*)&raw)[w];
            #pragma unroll
            for (int j = 0; j < 4; ++j)
                hv[w*4+j] = f2h_bits(0.25f * (float)((u >> (8*j)) & 0xFFu));
        }
        unsigned short* dst = sIn + tid*16;
        *(f16x8*)dst       = *(const f16x8*)&hv[0];
        *(f16x8*)(dst + 8) = *(const f16x8*)&hv[8];
    }
    __syncthreads();   // weights + t=0 staging visible

    #pragma unroll
    for (int nt = 0; nt < 2; ++nt) {
        int n = nt*16 + l15;
        #pragma unroll
        for (int kt = 0; kt < 7; ++kt)
            bfrH[nt][kt] = *(const f16x8*)&w2h[n*232 + kt*32 + kg*8];
    }

    float vst[2][2][4], ist[2][2][4];
    #pragma unroll
    for (int mt = 0; mt < 2; ++mt)
        #pragma unroll
        for (int nt = 0; nt < 2; ++nt)
            #pragma unroll
            for (int r = 0; r < 4; ++r) { vst[mt][nt][r] = 0.f; ist[mt][nt][r] = 0.f; }

    const f32x4 zero4 = {0.f, 0.f, 0.f, 0.f};

    for (int t = 0; t < T_STEPS; ++t) {
        if (t > 0) __syncthreads();   // staging of t + frees buffer (t+1)&1

        uint4 raw;
        if (t + 1 < T_STEPS)
            raw = *(const uint4*)(s0 + (size_t)((t+1)*BATCH + b)*4096 + tid*16);

        const char* curB = (const char*)(sIn + (t&1)*4096);

        f32x4 acch[2][2], accl[2][2];
        #pragma unroll
        for (int mt = 0; mt < 2; ++mt)
            #pragma unroll
            for (int nt = 0; nt < 2; ++nt) { acch[mt][nt] = zero4; accl[mt][nt] = zero4; }

        #pragma unroll
        for (int kt = 0; kt < 7; ++kt) {
            f16x8 bm[2];
            #pragma unroll
            for (int nt = 0; nt < 2; ++nt) {
                int n = nt*16 + l15, k = kt*32 + kg*8;
                bm[nt] = *(const f16x8*)&w2m[n*232 + k];
            }
            #pragma unroll
            for (int mt = 0; mt < 2; ++mt) {
                f16x8 a = *(const f16x8*)(curB + addrA[mt][kt]);
                #pragma unroll
                for (int nt = 0; nt < 2; ++nt) {
                    acch[mt][nt] = __builtin_amdgcn_mfma_f32_16x16x32_f16(
                        a, bfrH[nt][kt], acch[mt][nt], 0, 0, 0);
                    accl[mt][nt] = __builtin_amdgcn_mfma_f32_16x16x32_f16(
                        a, bm[nt], accl[mt][nt], 0, 0, 0);
                }
            }
        }

        size_t rowoff = (size_t)(t*BATCH + b) * 6208;
        #pragma unroll
        for (int mt = 0; mt < 2; ++mt) {
            int posb = wm*32 + mt*16 + kg*4;
            #pragma unroll
            for (int nt = 0; nt < 2; ++nt) {
                int ocn = half*32 + nt*16 + l15;
                u16x4 pack;
                #pragma unroll
                for (int r = 0; r < 4; ++r) {
                    float inp = __fadd_rn(acch[mt][nt][r], __fmul_rn(S2LO, accl[mt][nt][r]));
                    float z = lif_update(inp, vst[mt][nt][r], ist[mt][nt][r], 0.2f);
                    int pos = posb + r;
                    pack[r] = (pos <= 120 && z > 0.5f) ? (unsigned short)0x3C00 : (unsigned short)0;
                }
                if (ocn < 50 && posb < 121)
                    *(u16x4*)(z1 + rowoff + ocn*124 + posb) = pack;
            }
        }
        if (half == 0 && tid < 8) z1[rowoff + 6200 + tid] = 0;

        if (t + 1 < T_STEPS) {
            unsigned short hv[16];
            #pragma unroll
            for (int w = 0; w < 4; ++w) {
                unsigned int u = ((const unsigned int*)&raw)[w];
                #pragma unroll
                for (int j = 0; j < 4; ++j)
                    hv[w*4+j] = f2h_bits(0.25f * (float)((u >> (8*j)) & 0xFFu));
            }
            unsigned short* dst = sIn + ((t+1)&1)*4096 + tid*16;
            *(f16x8*)dst       = *(const f16x8*)&hv[0];
            *(f16x8*)(dst + 8) = *(const f16x8*)&hv[8];
        }
    }
}

// ---------------------------------------------------------------------------
// MFMA GEMM (fp16), m97 2-buffer, global_load_lds w16, XOR-swizzled LDS.
// blockIdx.z selects weight plane. 128x128 tile, BK=64.
// ---------------------------------------------------------------------------
__global__ __launch_bounds__(256, 3) void k_gemm(
    const unsigned short* __restrict__ A,
    const unsigned short* __restrict__ B0,
    float* __restrict__ C0,
    int Kp, int kiters, int ldc, int nstore,
    size_t strideB, size_t strideC)
{
    __shared__ __align__(16) unsigned short As[128*64];
    __shared__ __align__(16) unsigned short Bs[128*64];
    const unsigned short* B = B0 + (size_t)blockIdx.z * strideB;
    float* C = C0 + (size_t)blockIdx.z * strideC;

    const int tid  = threadIdx.x;
    const int lane = tid & 63;
    const int wv   = tid >> 6;
    const int wm   = wv & 1, wn = wv >> 1;
    const int l15  = lane & 15, kg = lane >> 4;
    const int mbase = blockIdx.x * 128;
    const int nbase = blockIdx.y * 128;

    const f32x4 zero4 = {0.f, 0.f, 0.f, 0.f};
    f32x4 acc[4][4];
    #pragma unroll
    for (int mt = 0; mt < 4; ++mt)
        #pragma unroll
        for (int nt = 0; nt < 4; ++nt) acc[mt][nt] = zero4;

    const int rowA = tid >> 3;                        // 0..31
    const int sw   = (((tid & 7) ^ (rowA & 7))) * 8;  // xor-swizzled chunk (elems)
    char* ldsA = (char*)As + (size_t)wv*1024;
    char* ldsB = (char*)Bs + (size_t)wv*1024;

    for (int ki = 0; ki < kiters; ++ki) {
        int kb = ki * 64;
        #pragma unroll
        for (int c = 0; c < 4; ++c) {
            int row = c*32 + rowA;
            llds16(A + (size_t)(mbase + row)*Kp + kb + sw, ldsA + c*4096);
            llds16(B + (size_t)(nbase + row)*Kp + kb + sw, ldsB + c*4096);
        }
        __syncthreads();
        #pragma unroll
        for (int kt = 0; kt < 2; ++kt) {
            f16x8 bfv[4], afv[4];
            #pragma unroll
            for (int nt = 0; nt < 4; ++nt) {
                int rb = wn*64 + nt*16 + l15;
                int ch = ((kt*4 + kg) ^ (rb & 7)) * 8;
                bfv[nt] = *(const f16x8*)&Bs[rb*64 + ch];
            }
            #pragma unroll
            for (int mt = 0; mt < 4; ++mt) {
                int ra = wm*64 + mt*16 + l15;
                int ch = ((kt*4 + kg) ^ (ra & 7)) * 8;
                afv[mt] = *(const f16x8*)&As[ra*64 + ch];
            }
            #pragma unroll
            for (int mt = 0; mt < 4; ++mt)
                #pragma unroll
                for (int nt = 0; nt < 4; ++nt)
                    acc[mt][nt] = __builtin_amdgcn_mfma_f32_16x16x32_f16(
                        afv[mt], bfv[nt], acc[mt][nt], 0, 0, 0);
        }
        __syncthreads();
    }

    #pragma unroll
    for (int mt = 0; mt < 4; ++mt) {
        int m0 = mbase + wm*64 + mt*16 + kg*4;
        #pragma unroll
        for (int nt = 0; nt < 4; ++nt) {
            int n = nbase + wn*64 + nt*16 + l15;
            if (n < nstore) {
                #pragma unroll
                for (int r = 0; r < 4; ++r)
                    C[(size_t)(m0 + r)*ldc + n] = acc[mt][nt][r];
            }
        }
    }
}

// Pack fp32 weights [N,K] -> zero-padded fp16 planes: hi=fp16(w), lo=fp16((w-hi)*2^12)
__global__ void k_pack(const float* __restrict__ src,
                       unsigned short* __restrict__ hi, unsigned short* __restrict__ lo,
                       int N, int K, int Kp, int total) {
    int idx = blockIdx.x*256 + threadIdx.x;
    if (idx >= total) return;
    int n = idx / Kp, k = idx - n*Kp;
    float v = (n < N && k < K) ? src[n*K + k] : 0.f;
    _Float16 h = (_Float16)v;
    float r1 = (v - (float)h) * 4096.0f;
    union { _Float16 h; unsigned short u; } ch, cl;
    ch.h = h; cl.h = (_Float16)r1;
    hi[idx] = ch.u;
    lo[idx] = cl.u;
}

// fc1 weight pack with (oc,pos) K-mapping: col k -> oc=k/124, pos=k%124;
// valid (oc<50, pos<121) -> src k' = oc*121+pos. Kp=6208.
__global__ void k_pack_fc1(const float* __restrict__ src,
                           unsigned short* __restrict__ hi, unsigned short* __restrict__ lo,
                           int total) {
    int idx = blockIdx.x*256 + threadIdx.x;
    if (idx >= total) return;
    int n = idx / 6208, k = idx - n*6208;
    int oc = k / 124, pos = k - oc*124;
    float v = (n < 500 && oc < 50 && pos < 121) ? src[n*6050 + oc*121 + pos] : 0.f;
    _Float16 h = (_Float16)v;
    float r1 = (v - (float)h) * 4096.0f;
    union { _Float16 h; unsigned short u; } ch, cl;
    ch.h = h; cl.h = (_Float16)r1;
    hi[idx] = ch.u;
    lo[idx] = cl.u;
}

// LIF scan over t for fc layers: s = hi_dot + 2^-12 * lo_dot, LIF recurrence.
__global__ __launch_bounds__(512) void k_lif_scan(
    const float* __restrict__ c0, size_t pstride,
    unsigned short* __restrict__ zout,
    int ld, int nvalid, float vth)
{
    int b = blockIdx.x;
    int n = threadIdx.x;
    float v = 0.f, cur = 0.f;
    for (int t = 0; t < T_STEPS; ++t) {
        size_t idx = (size_t)(t*BATCH + b)*ld + n;
        float s = __fadd_rn(c0[idx], __fmul_rn(S2LO, c0[idx + pstride]));
        float z = lif_update(s, v, cur, vth);
        zout[idx] = (n < nvalid && z > 0.5f) ? (unsigned short)0x3C00 : (unsigned short)0;
    }
}

// LI output cell scan: s = hi + 2^-12*lo; out[t] = decayed membrane (fp32)
__global__ void k_li(const float* __restrict__ c0, size_t pstride, float* __restrict__ out) {
    int g = blockIdx.x*64 + threadIdx.x;
    if (g >= 2560) return;
    int b = g / 10, n = g - b*10;
    float vo = 0.f, io = 0.f;
    for (int t = 0; t < T_STEPS; ++t) {
        size_t idx = (size_t)(t*BATCH + b)*16 + n;
        float s = __fadd_rn(c0[idx], __fmul_rn(S2LO, c0[idx + pstride]));
        float vd = __fadd_rn(vo, __fmul_rn(0.1f, __fsub_rn(io, vo)));
        out[(size_t)(t*BATCH + b)*10 + n] = vd;
        io = __fadd_rn(__fmul_rn(0.8f, io), s);
        vo = vd;
    }
}

extern "C" void kernel_launch(void* const* d_in, const int* in_sizes, int n_in,
                              void* d_out, int out_size, void* d_ws, size_t ws_size,
                              hipStream_t stream) {
    (void)in_sizes; (void)n_in; (void)out_size; (void)ws_size;
    const float* x   = (const float*)d_in[0];
    const float* w1  = (const float*)d_in[1];
    const float* w2  = (const float*)d_in[2];
    const float* wf1 = (const float*)d_in[3];
    const float* wf2 = (const float*)d_in[4];
    const float* wfo = (const float*)d_in[5];
    char* ws = (char*)d_ws;

    // ---- workspace layout (peak 182.5 MB < 208.4 MB proven writable r7/r8) ----
    // phase A (conv): z1 [0, 127,139,840)  10240 x 6208 fp16
    //                 s0 [127,139,840, 169,082,880)  10240 x 4096 u8
    // phase B (fc1):  z1 live; overlay dead s0:
    //   W1 [127,139,840, 139,853,824)   2 x [512][6208] fp16
    //   W2 [139,853,824, 140,378,112)   2 x [256][512]
    //   Wo [140,378,112, 140,509,184)   2 x [128][256]
    //   c2p[140,509,184, 182,452,224)   2 x [10240][512] fp32
    // phase C (fc2+): z1 dead; low region, disjoint:
    //   z2 [0, 10,485,760) ; c3p [10,485,760, 31,457,280) ;
    //   z3 [31,457,280, 36,700,160) ; c4p [36,700,160, 38,010,880)
    unsigned short* z1    = (unsigned short*)(ws);
    unsigned char*  s0    = (unsigned char*)(ws + 127139840);
    unsigned short* W1hi  = (unsigned short*)(ws + 127139840);
    unsigned short* W2hi  = (unsigned short*)(ws + 139853824);
    unsigned short* Wohi  = (unsigned short*)(ws + 140378112);
    float*          c2p   = (float*)(ws + 140509184);
    unsigned short* z2    = (unsigned short*)(ws);
    float*          c3p   = (float*)(ws + 10485760);
    unsigned short* z3    = (unsigned short*)(ws + 31457280);
    float*          c4p   = (float*)(ws + 36700160);

    k_conv1<<<256, 576, 0, stream>>>(x, w1, s0);
    k_conv2<<<512, 256, 0, stream>>>(s0, w2, z1);

    k_pack_fc1<<<(3178496+255)/256, 256, 0, stream>>>(wf1, W1hi, W1hi+3178496, 3178496);
    k_pack<<<(131072+255)/256, 256, 0, stream>>>(wf2, W2hi, W2hi+131072, 200, 500, 512, 131072);
    k_pack<<<(32768+255)/256,  256, 0, stream>>>(wfo, Wohi, Wohi+32768,  10,  200, 256, 32768);

    k_gemm<<<dim3(80,4,2), 256, 0, stream>>>(z1, W1hi, c2p, 6208, 97, 512, 512,
                                             (size_t)3178496, (size_t)5242880);
    k_lif_scan<<<256, 512, 0, stream>>>(c2p, (size_t)5242880, z2, 512, 500, 0.1f);
    k_gemm<<<dim3(80,2,2), 256, 0, stream>>>(z2, W2hi, c3p, 512, 8, 256, 256,
                                             (size_t)131072, (size_t)2621440);
    k_lif_scan<<<256, 256, 0, stream>>>(c3p, (size_t)2621440, z3, 256, 200, 0.05f);
    k_gemm<<<dim3(80,1,2), 256, 0, stream>>>(z3, Wohi, c4p, 256, 4, 16, 16,
                                             (size_t)32768, (size_t)163840);
    k_li<<<40, 64, 0, stream>>>(c4p, (size_t)163840, (float*)d_out);
}